// Round 1
// baseline (920.470 us; speedup 1.0000x reference)
//
#include <hip/hip_runtime.h>

#define B_  4
#define L_  1024
#define D_  1024
#define NH_ 16
#define DH_ 64
#define H_  2730
#define HP_ 2816
#define M_  4096  // B*L

typedef short bf16x8 __attribute__((ext_vector_type(8)));
typedef float f32x4  __attribute__((ext_vector_type(4)));

__device__ __forceinline__ unsigned short f2bf(float f) {
    unsigned int u = __builtin_bit_cast(unsigned int, f);
    u += 0x7fffu + ((u >> 16) & 1u);
    return (unsigned short)(u >> 16);
}
__device__ __forceinline__ float bf2f(unsigned short s) {
    unsigned int u = ((unsigned int)s) << 16;
    return __builtin_bit_cast(float, u);
}

// ---------------- weight fp32 -> bf16 (with zero padding) ----------------
__global__ __launch_bounds__(256) void cvt_pad_kernel(
    const float* __restrict__ in, unsigned short* __restrict__ out,
    int K, int N, int Np, long total)
{
    long idx = (long)blockIdx.x * 256 + threadIdx.x;
    if (idx >= total) return;
    int k = (int)(idx / Np), n = (int)(idx % Np);
    float v = (n < N && k < K) ? in[(size_t)k * N + n] : 0.0f;
    out[idx] = f2bf(v);
}

// ---------------- RMSNorm: fp32 in -> bf16 out ----------------
__global__ __launch_bounds__(256) void rmsnorm_kernel(
    const float* __restrict__ x, const float* __restrict__ w,
    unsigned short* __restrict__ out)
{
    const int row = blockIdx.x;
    const int t = threadIdx.x;
    const float4 v = ((const float4*)(x + (size_t)row * 1024))[t];
    float ss = v.x*v.x + v.y*v.y + v.z*v.z + v.w*v.w;
    #pragma unroll
    for (int off = 32; off > 0; off >>= 1) ss += __shfl_down(ss, off);
    __shared__ float red[4];
    if ((t & 63) == 0) red[t >> 6] = ss;
    __syncthreads();
    const float tot = red[0] + red[1] + red[2] + red[3];
    const float rr = rsqrtf(tot * (1.0f / 1024.0f) + 1e-8f);
    const float4 wv = ((const float4*)w)[t];
    ushort4 o;
    o.x = f2bf(v.x * wv.x * rr); o.y = f2bf(v.y * wv.y * rr);
    o.z = f2bf(v.z * wv.z * rr); o.w = f2bf(v.w * wv.w * rr);
    ((ushort4*)(out + (size_t)row * 1024))[t] = o;
}

// ---------------- bf16 MFMA GEMM, 128x128 tile, BK=32, 4 waves ----------------
// EPI: 0 = out_bf16(acc + bias)            (qkv)
//      1 = out_f32(acc + bias + res)       (wo: x + head@wo + bo)
//      2 = out_bf16(acc)                   (tv = xn@v)
//      3 = out_bf16(silu(acc) * mul)       (g)
//      4 = out_f32(acc + res)              (out = x2 + g@w)
template<int EPI>
__global__ __launch_bounds__(256) void gemm_bf16(
    const unsigned short* __restrict__ A, const unsigned short* __restrict__ Bm,
    int M, int N, int K,
    const float* __restrict__ bias, const float* __restrict__ res,
    const unsigned short* __restrict__ mul,
    float* __restrict__ outf, unsigned short* __restrict__ outb)
{
    __shared__ unsigned short As[128 * 40];  // [m][k], +8 pad
    __shared__ unsigned short Bs[128 * 40];  // [n][k] (transposed), +8 pad
    const int tid = threadIdx.x;
    const int bx = blockIdx.x, by = blockIdx.y;
    const int m0 = by * 128, n0 = bx * 128;
    const int lane = tid & 63, wv = tid >> 6;
    const int wm = wv >> 1, wn = wv & 1;
    const int quad = lane >> 4, l15 = lane & 15;

    f32x4 acc[4][4] = {};

    const int arow = tid >> 1, aseg = tid & 1;     // A staging: 32B per thread
    const int bk = tid >> 3, bn = (tid & 7) * 16;  // B staging: 32B per thread

    for (int k0 = 0; k0 < K; k0 += 32) {
        const unsigned short* ap = A + (size_t)(m0 + arow) * K + k0 + aseg * 16;
        uint4 a0 = *(const uint4*)ap;
        uint4 a1 = *(const uint4*)(ap + 8);
        const unsigned short* bp = Bm + (size_t)(k0 + bk) * N + n0 + bn;
        uint4 b0 = *(const uint4*)bp;
        uint4 b1 = *(const uint4*)(bp + 8);
        *(uint4*)&As[arow * 40 + aseg * 16]     = a0;
        *(uint4*)&As[arow * 40 + aseg * 16 + 8] = a1;
        union { uint4 u; unsigned short s[8]; } ub0, ub1;
        ub0.u = b0; ub1.u = b1;
        #pragma unroll
        for (int j = 0; j < 8; ++j) Bs[(bn + j) * 40 + bk] = ub0.s[j];
        #pragma unroll
        for (int j = 0; j < 8; ++j) Bs[(bn + 8 + j) * 40 + bk] = ub1.s[j];
        __syncthreads();

        bf16x8 af[4], bfr[4];
        #pragma unroll
        for (int ms = 0; ms < 4; ++ms)
            af[ms] = *(const bf16x8*)&As[(wm * 64 + ms * 16 + l15) * 40 + quad * 8];
        #pragma unroll
        for (int ns = 0; ns < 4; ++ns)
            bfr[ns] = *(const bf16x8*)&Bs[(wn * 64 + ns * 16 + l15) * 40 + quad * 8];
        #pragma unroll
        for (int ms = 0; ms < 4; ++ms)
            #pragma unroll
            for (int ns = 0; ns < 4; ++ns)
                acc[ms][ns] = __builtin_amdgcn_mfma_f32_16x16x32_bf16(
                    af[ms], bfr[ns], acc[ms][ns], 0, 0, 0);
        __syncthreads();
    }

    #pragma unroll
    for (int ms = 0; ms < 4; ++ms) {
        #pragma unroll
        for (int r = 0; r < 4; ++r) {
            const int row = m0 + wm * 64 + ms * 16 + quad * 4 + r;
            const size_t ro = (size_t)row * N;
            #pragma unroll
            for (int ns = 0; ns < 4; ++ns) {
                const int col = n0 + wn * 64 + ns * 16 + l15;
                float v = acc[ms][ns][r];
                if (EPI == 0) {
                    outb[ro + col] = f2bf(v + bias[col]);
                } else if (EPI == 1) {
                    outf[ro + col] = v + bias[col] + res[ro + col];
                } else if (EPI == 2) {
                    outb[ro + col] = f2bf(v);
                } else if (EPI == 3) {
                    float t = bf2f(mul[ro + col]);
                    float g = v / (1.0f + __expf(-v)) * t;
                    outb[ro + col] = f2bf(g);
                } else {
                    outf[ro + col] = v + res[ro + col];
                }
            }
        }
    }
}

// ---------------- flash attention, fp32 SIMT, 64-query tiles ----------------
__global__ __launch_bounds__(256) void attn_kernel(
    const unsigned short* __restrict__ qkv, unsigned short* __restrict__ hout)
{
    __shared__ float Qs[64 * 66];
    __shared__ float Ks[64 * 66];
    __shared__ float Vs[64 * 68];
    __shared__ float Sc[64 * 65];
    const int tid = threadIdx.x;
    const int qt = blockIdx.x, h = blockIdx.y, b = blockIdx.z;
    const int q0 = qt * 64;
    const float scale = 0.03125f;  // D^-0.5 = 1/32 (reference uses d, not dh)

    const int srow = tid >> 2, sdc = tid & 3;  // staging / softmax-PV mapping
    {
        const unsigned short* qp = qkv + ((size_t)(b * L_ + q0 + srow) * 3072) + h * 64 + sdc * 16;
        union { uint4 u; unsigned short s[8]; } r0, r1;
        r0.u = *(const uint4*)qp; r1.u = *(const uint4*)(qp + 8);
        #pragma unroll
        for (int i = 0; i < 8; ++i) Qs[srow * 66 + sdc * 16 + i] = bf2f(r0.s[i]) * scale;
        #pragma unroll
        for (int i = 0; i < 8; ++i) Qs[srow * 66 + sdc * 16 + 8 + i] = bf2f(r1.s[i]) * scale;
    }
    float4 o[4] = {};
    float m_i = -1e30f, l_i = 0.0f;

    const int tq = tid >> 4, tk = tid & 15;  // score-phase mapping
    const int ql = srow, dc = sdc;

    for (int kt = 0; kt <= qt; ++kt) {
        const int k0 = kt * 64;
        __syncthreads();
        {
            const unsigned short* kp = qkv + ((size_t)(b * L_ + k0 + srow) * 3072) + 1024 + h * 64 + sdc * 16;
            union { uint4 u; unsigned short s[8]; } r0, r1;
            r0.u = *(const uint4*)kp; r1.u = *(const uint4*)(kp + 8);
            #pragma unroll
            for (int i = 0; i < 8; ++i) Ks[srow * 66 + sdc * 16 + i] = bf2f(r0.s[i]);
            #pragma unroll
            for (int i = 0; i < 8; ++i) Ks[srow * 66 + sdc * 16 + 8 + i] = bf2f(r1.s[i]);
            const unsigned short* vp = kp + 1024;
            r0.u = *(const uint4*)vp; r1.u = *(const uint4*)(vp + 8);
            #pragma unroll
            for (int i = 0; i < 8; ++i) Vs[srow * 68 + sdc * 16 + i] = bf2f(r0.s[i]);
            #pragma unroll
            for (int i = 0; i < 8; ++i) Vs[srow * 68 + sdc * 16 + 8 + i] = bf2f(r1.s[i]);
        }
        __syncthreads();
        // scores: 4 queries (4*tq+i) x 4 keys (tk+16*j)
        float sacc[4][4] = {};
        for (int d2 = 0; d2 < 32; ++d2) {
            float2 kv[4];
            #pragma unroll
            for (int j = 0; j < 4; ++j) kv[j] = *(const float2*)&Ks[(tk + 16 * j) * 66 + d2 * 2];
            #pragma unroll
            for (int i = 0; i < 4; ++i) {
                float2 qv = *(const float2*)&Qs[(tq * 4 + i) * 66 + d2 * 2];
                #pragma unroll
                for (int j = 0; j < 4; ++j)
                    sacc[i][j] += qv.x * kv[j].x + qv.y * kv[j].y;
            }
        }
        const bool diag = (kt == qt);
        #pragma unroll
        for (int i = 0; i < 4; ++i)
            #pragma unroll
            for (int j = 0; j < 4; ++j) {
                float v = sacc[i][j];
                if (diag && (tk + 16 * j) > (tq * 4 + i)) v = -1e30f;
                Sc[(tq * 4 + i) * 65 + tk + 16 * j] = v;
            }
        __syncthreads();
        // online softmax + PV  (thread owns query ql, dims dc*16..dc*16+15)
        float mold = m_i;
        float mx = mold;
        for (int j = 0; j < 64; ++j) mx = fmaxf(mx, Sc[ql * 65 + j]);
        float alpha = __expf(mold - mx);
        float sum = 0.0f;
        for (int j = 0; j < 64; ++j) {
            float p = __expf(Sc[ql * 65 + j] - mx);
            Sc[ql * 65 + j] = p;  // 4 dup threads write identical value: benign
            sum += p;
        }
        m_i = mx; l_i = l_i * alpha + sum;
        #pragma unroll
        for (int c = 0; c < 4; ++c) { o[c].x *= alpha; o[c].y *= alpha; o[c].z *= alpha; o[c].w *= alpha; }
        for (int j = 0; j < 64; ++j) {
            float p = Sc[ql * 65 + j];
            #pragma unroll
            for (int c = 0; c < 4; ++c) {
                const float4 vv = *(const float4*)&Vs[j * 68 + dc * 16 + c * 4];
                o[c].x += p * vv.x; o[c].y += p * vv.y; o[c].z += p * vv.z; o[c].w += p * vv.w;
            }
        }
    }
    const float inv = 1.0f / l_i;
    unsigned short* op = hout + ((size_t)(b * L_ + q0 + ql) * 1024) + h * 64 + dc * 16;
    #pragma unroll
    for (int c = 0; c < 4; ++c) {
        ushort4 st;
        st.x = f2bf(o[c].x * inv); st.y = f2bf(o[c].y * inv);
        st.z = f2bf(o[c].z * inv); st.w = f2bf(o[c].w * inv);
        *(ushort4*)(op + c * 4) = st;
    }
}

extern "C" void kernel_launch(void* const* d_in, const int* in_sizes, int n_in,
                              void* d_out, int out_size, void* d_ws, size_t ws_size,
                              hipStream_t stream)
{
    const float* x   = (const float*)d_in[0];
    // d_in[1] = mask m — causal, implemented analytically
    const float* wx  = (const float*)d_in[2];
    const float* bx  = (const float*)d_in[3];
    const float* wo  = (const float*)d_in[4];
    const float* bo  = (const float*)d_in[5];
    const float* mhw = (const float*)d_in[6];
    const float* ffw = (const float*)d_in[7];
    const float* u   = (const float*)d_in[8];
    const float* v   = (const float*)d_in[9];
    const float* w   = (const float*)d_in[10];
    float* out = (float*)d_out;

    char* W = (char*)d_ws;
    unsigned short* xn_bf   = (unsigned short*)(W + 0);          //  8 MB [4096,1024]
    unsigned short* wx_bf   = (unsigned short*)(W + 8388608);    //  6 MB [1024,3072]
    unsigned short* qkv_bf  = (unsigned short*)(W + 14680064);   // 24 MB [4096,3072]
    unsigned short* head_bf = (unsigned short*)(W + 39845888);   //  8 MB [4096,1024]
    unsigned short* wo_bf   = (unsigned short*)(W + 48234496);   //  2 MB [1024,1024]
    float*          x2      = (float*)(W + 50331648);            // 16 MB [4096,1024]
    unsigned short* u_bf    = (unsigned short*)(W + 67108864);   // 5.5 MB [1024,2816]
    unsigned short* v_bf    = (unsigned short*)(W + 72876032);   // 5.5 MB [1024,2816]
    unsigned short* w_bf    = (unsigned short*)(W + 78643200);   // 5.5 MB [2816,1024]
    unsigned short* g_bf    = (unsigned short*)(W + 84410368);   // 22 MB [4096,2816]
    unsigned short* tv_bf   = qkv_bf;  // alias: qkv dead after attention

    cvt_pad_kernel<<<(1024 * 3072) / 256, 256, 0, stream>>>(wx, wx_bf, 1024, 3072, 3072, 1024L * 3072);
    cvt_pad_kernel<<<(1024 * 1024) / 256, 256, 0, stream>>>(wo, wo_bf, 1024, 1024, 1024, 1024L * 1024);
    cvt_pad_kernel<<<(1024 * 2816) / 256, 256, 0, stream>>>(u,  u_bf, 1024, 2730, 2816, 1024L * 2816);
    cvt_pad_kernel<<<(1024 * 2816) / 256, 256, 0, stream>>>(v,  v_bf, 1024, 2730, 2816, 1024L * 2816);
    cvt_pad_kernel<<<(2816 * 1024) / 256, 256, 0, stream>>>(w,  w_bf, 2730, 1024, 1024, 2816L * 1024);

    rmsnorm_kernel<<<4096, 256, 0, stream>>>(x, mhw, xn_bf);

    gemm_bf16<0><<<dim3(3072 / 128, 4096 / 128), 256, 0, stream>>>(
        xn_bf, wx_bf, 4096, 3072, 1024, bx, nullptr, nullptr, nullptr, qkv_bf);

    attn_kernel<<<dim3(16, 16, 4), 256, 0, stream>>>(qkv_bf, head_bf);

    gemm_bf16<1><<<dim3(1024 / 128, 4096 / 128), 256, 0, stream>>>(
        head_bf, wo_bf, 4096, 1024, 1024, bo, x, nullptr, x2, nullptr);

    rmsnorm_kernel<<<4096, 256, 0, stream>>>(x2, ffw, xn_bf);

    gemm_bf16<2><<<dim3(2816 / 128, 4096 / 128), 256, 0, stream>>>(
        xn_bf, v_bf, 4096, 2816, 1024, nullptr, nullptr, nullptr, nullptr, tv_bf);

    gemm_bf16<3><<<dim3(2816 / 128, 4096 / 128), 256, 0, stream>>>(
        xn_bf, u_bf, 4096, 2816, 1024, nullptr, nullptr, tv_bf, nullptr, g_bf);

    gemm_bf16<4><<<dim3(1024 / 128, 4096 / 128), 256, 0, stream>>>(
        g_bf, w_bf, 4096, 1024, 2816, nullptr, x2, nullptr, out, nullptr);
}

// Round 2
// 446.412 us; speedup vs baseline: 2.0619x; 2.0619x over previous
//
#include <hip/hip_runtime.h>

#define B_  4
#define L_  1024
#define D_  1024
#define NH_ 16
#define DH_ 64
#define H_  2730
#define HP_ 2816
#define M_  4096  // B*L

typedef short bf16x8 __attribute__((ext_vector_type(8)));
typedef float f32x4  __attribute__((ext_vector_type(4)));

__device__ __forceinline__ unsigned short f2bf(float f) {
    unsigned int u = __builtin_bit_cast(unsigned int, f);
    u += 0x7fffu + ((u >> 16) & 1u);
    return (unsigned short)(u >> 16);
}
__device__ __forceinline__ float bf2f(unsigned short s) {
    unsigned int u = ((unsigned int)s) << 16;
    return __builtin_bit_cast(float, u);
}

__device__ __forceinline__ void glds16(const void* g, void* l) {
    __builtin_amdgcn_global_load_lds(
        (const __attribute__((address_space(1))) unsigned int*)g,
        (__attribute__((address_space(3))) unsigned int*)l, 16, 0, 0);
}

// ---------------- weight fp32 [K][N] -> bf16 transposed [Np][Kp] (zero pad) ----------------
__global__ __launch_bounds__(256) void cvtT_kernel(
    const float* __restrict__ in, unsigned short* __restrict__ out,
    int K, int N, int Kp, int Np)
{
    __shared__ float t[32][33];
    const int k0 = blockIdx.x * 32, n0 = blockIdx.y * 32;
    const int tx = threadIdx.x & 31, ty = threadIdx.x >> 5;
    #pragma unroll
    for (int i = 0; i < 4; ++i) {
        const int k = k0 + ty + i * 8, n = n0 + tx;
        t[ty + i * 8][tx] = (k < K && n < N) ? in[(size_t)k * N + n] : 0.0f;
    }
    __syncthreads();
    #pragma unroll
    for (int i = 0; i < 4; ++i) {
        const int n = n0 + ty + i * 8, k = k0 + tx;
        out[(size_t)n * Kp + k] = f2bf(t[tx][ty + i * 8]);
    }
}

// ---------------- RMSNorm: fp32 in -> bf16 out ----------------
__global__ __launch_bounds__(256) void rmsnorm_kernel(
    const float* __restrict__ x, const float* __restrict__ w,
    unsigned short* __restrict__ out)
{
    const int row = blockIdx.x;
    const int t = threadIdx.x;
    const float4 v = ((const float4*)(x + (size_t)row * 1024))[t];
    float ss = v.x*v.x + v.y*v.y + v.z*v.z + v.w*v.w;
    #pragma unroll
    for (int off = 32; off > 0; off >>= 1) ss += __shfl_down(ss, off);
    __shared__ float red[4];
    if ((t & 63) == 0) red[t >> 6] = ss;
    __syncthreads();
    const float tot = red[0] + red[1] + red[2] + red[3];
    const float rr = rsqrtf(tot * (1.0f / 1024.0f) + 1e-8f);
    const float4 wv = ((const float4*)w)[t];
    ushort4 o;
    o.x = f2bf(v.x * wv.x * rr); o.y = f2bf(v.y * wv.y * rr);
    o.z = f2bf(v.z * wv.z * rr); o.w = f2bf(v.w * wv.w * rr);
    ((ushort4*)(out + (size_t)row * 1024))[t] = o;
}

// ---------------- bf16 MFMA GEMM, 128x128 tile, BK=32, global_load_lds staging ----------------
// A [M][K] rows, Bt [N][K] rows (transposed weights).
// EPI: 0 = out_bf16(acc + bias)            (qkv)
//      1 = out_f32(acc + bias + res)       (wo: x + head@wo + bo)
//      2 = out_bf16(acc)                   (tv = xn@v)
//      3 = out_bf16(silu(acc) * mul)       (g)
//      4 = out_f32(acc + res)              (out = x2 + g@w)
template<int EPI>
__global__ __launch_bounds__(256) void gemm_bf16(
    const unsigned short* __restrict__ A, const unsigned short* __restrict__ Bt,
    int M, int N, int K,
    const float* __restrict__ bias, const float* __restrict__ res,
    const unsigned short* __restrict__ mul,
    float* __restrict__ outf, unsigned short* __restrict__ outb)
{
    __shared__ __align__(16) unsigned short As[128 * 32];
    __shared__ __align__(16) unsigned short Bs[128 * 32];
    const int tid = threadIdx.x;
    const int m0 = blockIdx.y * 128, n0 = blockIdx.x * 128;
    const int lane = tid & 63, w = tid >> 6;
    const int wm = w >> 1, wn = w & 1;
    const int quad = lane >> 4, l15 = lane & 15;

    f32x4 acc[4][4] = {};

    // staging: p = (i*4+w)*64 + lane -> row = p>>2, pos = p&3; global block = pos ^ (row&3)
    const int p0 = w * 64 + lane;
    const int p1 = (4 + w) * 64 + lane;
    const int r0 = p0 >> 2, c0 = (p0 & 3) ^ (r0 & 3);
    const int r1 = p1 >> 2, c1 = (p1 & 3) ^ (r1 & 3);

    const unsigned short* Ag0 = A + (size_t)(m0 + r0) * K + c0 * 8;
    const unsigned short* Ag1 = A + (size_t)(m0 + r1) * K + c1 * 8;
    const unsigned short* Bg0 = Bt + (size_t)(n0 + r0) * K + c0 * 8;
    const unsigned short* Bg1 = Bt + (size_t)(n0 + r1) * K + c1 * 8;
    unsigned short* lA0 = &As[w * 512];
    unsigned short* lA1 = &As[(4 + w) * 512];
    unsigned short* lB0 = &Bs[w * 512];
    unsigned short* lB1 = &Bs[(4 + w) * 512];

    for (int k0 = 0; k0 < K; k0 += 32) {
        glds16(Ag0 + k0, lA0);
        glds16(Ag1 + k0, lA1);
        glds16(Bg0 + k0, lB0);
        glds16(Bg1 + k0, lB1);
        __syncthreads();

        bf16x8 af[4], bfr[4];
        #pragma unroll
        for (int ms = 0; ms < 4; ++ms) {
            const int row = wm * 64 + ms * 16 + l15;
            af[ms] = *(const bf16x8*)&As[row * 32 + ((quad ^ (row & 3)) * 8)];
        }
        #pragma unroll
        for (int ns = 0; ns < 4; ++ns) {
            const int row = wn * 64 + ns * 16 + l15;
            bfr[ns] = *(const bf16x8*)&Bs[row * 32 + ((quad ^ (row & 3)) * 8)];
        }
        #pragma unroll
        for (int ms = 0; ms < 4; ++ms)
            #pragma unroll
            for (int ns = 0; ns < 4; ++ns)
                acc[ms][ns] = __builtin_amdgcn_mfma_f32_16x16x32_bf16(
                    af[ms], bfr[ns], acc[ms][ns], 0, 0, 0);
        __syncthreads();
    }

    #pragma unroll
    for (int ms = 0; ms < 4; ++ms) {
        #pragma unroll
        for (int r = 0; r < 4; ++r) {
            const int row = m0 + wm * 64 + ms * 16 + quad * 4 + r;
            const size_t ro = (size_t)row * N;
            #pragma unroll
            for (int ns = 0; ns < 4; ++ns) {
                const int col = n0 + wn * 64 + ns * 16 + l15;
                float v = acc[ms][ns][r];
                if (EPI == 0) {
                    outb[ro + col] = f2bf(v + bias[col]);
                } else if (EPI == 1) {
                    outf[ro + col] = v + bias[col] + res[ro + col];
                } else if (EPI == 2) {
                    outb[ro + col] = f2bf(v);
                } else if (EPI == 3) {
                    float t = bf2f(mul[ro + col]);
                    float g = v / (1.0f + __expf(-v)) * t;
                    outb[ro + col] = f2bf(g);
                } else {
                    outf[ro + col] = v + res[ro + col];
                }
            }
        }
    }
}

// ---------------- MFMA flash attention: 128-query blocks, 64-key tiles ----------------
__global__ __launch_bounds__(256) void attn_mfma_kernel(
    const unsigned short* __restrict__ qkv, unsigned short* __restrict__ hout)
{
    __shared__ __align__(16) unsigned short Qs[128 * 72];
    __shared__ __align__(16) unsigned short Ks[64 * 72];
    __shared__ __align__(16) unsigned short Vt[64 * 72];  // [d][key]
    __shared__ __align__(16) unsigned short Ps[128 * 72];

    const int tid = threadIdx.x;
    const int qt = blockIdx.x, h = blockIdx.y, b = blockIdx.z;
    const int q0 = qt * 128;
    const int w = tid >> 6, lane = tid & 63;
    const int quad = lane >> 4, l15 = lane & 15;

    // stage Q once: thread -> row=tid>>1, half=tid&1 (32 elems = 64B)
    {
        const int row = tid >> 1, half = tid & 1;
        const unsigned short* gp = qkv + (size_t)(b * L_ + q0 + row) * 3072 + h * 64 + half * 32;
        uint4 a = *(const uint4*)gp;
        uint4 c = *(const uint4*)(gp + 8);
        uint4 d = *(const uint4*)(gp + 16);
        uint4 e = *(const uint4*)(gp + 24);
        unsigned short* dp = &Qs[row * 72 + half * 32];
        *(uint4*)dp = a; *(uint4*)(dp + 8) = c; *(uint4*)(dp + 16) = d; *(uint4*)(dp + 24) = e;
    }

    f32x4 O[2][4] = {};
    float m_st[2][4], l_st[2][4];
    #pragma unroll
    for (int qs = 0; qs < 2; ++qs)
        #pragma unroll
        for (int r = 0; r < 4; ++r) { m_st[qs][r] = -1e30f; l_st[qs][r] = 0.0f; }

    const int ktiles = 2 * qt + 2;
    const int wave_qmax = q0 + w * 32 + 31;
    const int krow = tid >> 2, kseg = tid & 3;
    const int vkey = (tid & 31) * 2, vdp = tid >> 5;

    for (int kt = 0; kt < ktiles; ++kt) {
        const int k0 = kt * 64;
        __syncthreads();
        {   // stage K [key][d]
            const unsigned short* gp = qkv + (size_t)(b * L_ + k0 + krow) * 3072 + 1024 + h * 64 + kseg * 16;
            uint4 a = *(const uint4*)gp;
            uint4 c = *(const uint4*)(gp + 8);
            unsigned short* dp = &Ks[krow * 72 + kseg * 16];
            *(uint4*)dp = a; *(uint4*)(dp + 8) = c;
        }
        {   // stage V transposed [d][key], packed pair writes (conflict-free)
            const unsigned short* gp = qkv + (size_t)(b * L_ + k0 + vkey) * 3072 + 2048 + h * 64 + vdp * 8;
            union { uint4 u; unsigned short s[8]; } v0, v1;
            v0.u = *(const uint4*)gp;
            v1.u = *(const uint4*)(gp + 3072);
            #pragma unroll
            for (int i = 0; i < 8; ++i) {
                unsigned int pk = (unsigned int)v0.s[i] | ((unsigned int)v1.s[i] << 16);
                *(unsigned int*)&Vt[(vdp * 8 + i) * 72 + vkey] = pk;
            }
        }
        __syncthreads();

        if (k0 <= wave_qmax) {
            // ---- S = Q K^T (16 MFMA) ----
            bf16x8 af[2][2], bfk[4][2];
            #pragma unroll
            for (int qs = 0; qs < 2; ++qs)
                #pragma unroll
                for (int s = 0; s < 2; ++s)
                    af[qs][s] = *(const bf16x8*)&Qs[(w * 32 + qs * 16 + l15) * 72 + s * 32 + quad * 8];
            #pragma unroll
            for (int n = 0; n < 4; ++n)
                #pragma unroll
                for (int s = 0; s < 2; ++s)
                    bfk[n][s] = *(const bf16x8*)&Ks[(n * 16 + l15) * 72 + s * 32 + quad * 8];
            f32x4 sacc[2][4] = {};
            #pragma unroll
            for (int qs = 0; qs < 2; ++qs)
                #pragma unroll
                for (int n = 0; n < 4; ++n) {
                    sacc[qs][n] = __builtin_amdgcn_mfma_f32_16x16x32_bf16(af[qs][0], bfk[n][0], sacc[qs][n], 0, 0, 0);
                    sacc[qs][n] = __builtin_amdgcn_mfma_f32_16x16x32_bf16(af[qs][1], bfk[n][1], sacc[qs][n], 0, 0, 0);
                }

            // ---- scale + mask + online softmax + P -> LDS ----
            #pragma unroll
            for (int qs = 0; qs < 2; ++qs) {
                const int rowg0 = q0 + w * 32 + qs * 16 + quad * 4;
                float p[4][4], mx[4];
                #pragma unroll
                for (int r = 0; r < 4; ++r) mx[r] = -1e30f;
                #pragma unroll
                for (int n = 0; n < 4; ++n) {
                    const int col = k0 + n * 16 + l15;
                    #pragma unroll
                    for (int r = 0; r < 4; ++r) {
                        float v = sacc[qs][n][r] * 0.03125f;
                        if (col > rowg0 + r) v = -1e30f;
                        p[n][r] = v;
                        mx[r] = fmaxf(mx[r], v);
                    }
                }
                #pragma unroll
                for (int r = 0; r < 4; ++r) {
                    #pragma unroll
                    for (int m = 1; m < 16; m <<= 1)
                        mx[r] = fmaxf(mx[r], __shfl_xor(mx[r], m));
                }
                float alpha[4], rs[4];
                #pragma unroll
                for (int r = 0; r < 4; ++r) {
                    const float mnew = fmaxf(m_st[qs][r], mx[r]);
                    alpha[r] = __expf(m_st[qs][r] - mnew);
                    m_st[qs][r] = mnew;
                    float s0 = 0.0f;
                    #pragma unroll
                    for (int n = 0; n < 4; ++n) {
                        const float e = __expf(p[n][r] - mnew);
                        p[n][r] = e;
                        s0 += e;
                    }
                    rs[r] = s0;
                }
                #pragma unroll
                for (int r = 0; r < 4; ++r) {
                    #pragma unroll
                    for (int m = 1; m < 16; m <<= 1)
                        rs[r] += __shfl_xor(rs[r], m);
                    l_st[qs][r] = l_st[qs][r] * alpha[r] + rs[r];
                }
                #pragma unroll
                for (int dn = 0; dn < 4; ++dn)
                    #pragma unroll
                    for (int r = 0; r < 4; ++r)
                        O[qs][dn][r] *= alpha[r];
                #pragma unroll
                for (int n = 0; n < 4; ++n)
                    #pragma unroll
                    for (int r = 0; r < 4; ++r)
                        Ps[(w * 32 + qs * 16 + quad * 4 + r) * 72 + n * 16 + l15] = f2bf(p[n][r]);
            }

            // ---- O += P V (16 MFMA) ----
            bf16x8 ap[2][2], bv[4][2];
            #pragma unroll
            for (int qs = 0; qs < 2; ++qs)
                #pragma unroll
                for (int s = 0; s < 2; ++s)
                    ap[qs][s] = *(const bf16x8*)&Ps[(w * 32 + qs * 16 + l15) * 72 + s * 32 + quad * 8];
            #pragma unroll
            for (int dn = 0; dn < 4; ++dn)
                #pragma unroll
                for (int s = 0; s < 2; ++s)
                    bv[dn][s] = *(const bf16x8*)&Vt[(dn * 16 + l15) * 72 + s * 32 + quad * 8];
            #pragma unroll
            for (int qs = 0; qs < 2; ++qs)
                #pragma unroll
                for (int dn = 0; dn < 4; ++dn) {
                    O[qs][dn] = __builtin_amdgcn_mfma_f32_16x16x32_bf16(ap[qs][0], bv[dn][0], O[qs][dn], 0, 0, 0);
                    O[qs][dn] = __builtin_amdgcn_mfma_f32_16x16x32_bf16(ap[qs][1], bv[dn][1], O[qs][dn], 0, 0, 0);
                }
        }
    }

    // epilogue: normalize + store
    #pragma unroll
    for (int qs = 0; qs < 2; ++qs) {
        #pragma unroll
        for (int r = 0; r < 4; ++r) {
            const float inv = 1.0f / l_st[qs][r];
            const int rowg = q0 + w * 32 + qs * 16 + quad * 4 + r;
            unsigned short* op = hout + (size_t)(b * L_ + rowg) * 1024 + h * 64;
            #pragma unroll
            for (int dn = 0; dn < 4; ++dn)
                op[dn * 16 + l15] = f2bf(O[qs][dn][r] * inv);
        }
    }
}

extern "C" void kernel_launch(void* const* d_in, const int* in_sizes, int n_in,
                              void* d_out, int out_size, void* d_ws, size_t ws_size,
                              hipStream_t stream)
{
    const float* x   = (const float*)d_in[0];
    // d_in[1] = mask m — causal, implemented analytically
    const float* wx  = (const float*)d_in[2];
    const float* bx  = (const float*)d_in[3];
    const float* wo  = (const float*)d_in[4];
    const float* bo  = (const float*)d_in[5];
    const float* mhw = (const float*)d_in[6];
    const float* ffw = (const float*)d_in[7];
    const float* u   = (const float*)d_in[8];
    const float* v   = (const float*)d_in[9];
    const float* w   = (const float*)d_in[10];
    float* out = (float*)d_out;

    char* W = (char*)d_ws;
    unsigned short* xn_bf   = (unsigned short*)(W + 0);          //  8 MB [4096,1024]
    unsigned short* wx_bf   = (unsigned short*)(W + 8388608);    //  6 MB [3072,1024] (T)
    unsigned short* qkv_bf  = (unsigned short*)(W + 14680064);   // 24 MB [4096,3072]
    unsigned short* head_bf = (unsigned short*)(W + 39845888);   //  8 MB [4096,1024]
    unsigned short* wo_bf   = (unsigned short*)(W + 48234496);   //  2 MB [1024,1024] (T)
    float*          x2      = (float*)(W + 50331648);            // 16 MB [4096,1024]
    unsigned short* u_bf    = (unsigned short*)(W + 67108864);   // 5.5 MB [2816,1024] (T)
    unsigned short* v_bf    = (unsigned short*)(W + 72876032);   // 5.5 MB [2816,1024] (T)
    unsigned short* w_bf    = (unsigned short*)(W + 78643200);   // 5.5 MB [1024,2816] (T)
    unsigned short* g_bf    = (unsigned short*)(W + 84410368);   // 22 MB [4096,2816]
    unsigned short* tv_bf   = qkv_bf;  // alias: qkv dead after attention

    // transposed bf16 weight conversion: in [K][N] -> out [Np][Kp]
    cvtT_kernel<<<dim3(32, 96), 256, 0, stream>>>(wx, wx_bf, 1024, 3072, 1024, 3072);
    cvtT_kernel<<<dim3(32, 32), 256, 0, stream>>>(wo, wo_bf, 1024, 1024, 1024, 1024);
    cvtT_kernel<<<dim3(32, 88), 256, 0, stream>>>(u,  u_bf, 1024, 2730, 1024, 2816);
    cvtT_kernel<<<dim3(32, 88), 256, 0, stream>>>(v,  v_bf, 1024, 2730, 1024, 2816);
    cvtT_kernel<<<dim3(88, 32), 256, 0, stream>>>(w,  w_bf, 2730, 1024, 2816, 1024);

    rmsnorm_kernel<<<4096, 256, 0, stream>>>(x, mhw, xn_bf);

    gemm_bf16<0><<<dim3(3072 / 128, 4096 / 128), 256, 0, stream>>>(
        xn_bf, wx_bf, 4096, 3072, 1024, bx, nullptr, nullptr, nullptr, qkv_bf);

    attn_mfma_kernel<<<dim3(8, 16, 4), 256, 0, stream>>>(qkv_bf, head_bf);

    gemm_bf16<1><<<dim3(1024 / 128, 4096 / 128), 256, 0, stream>>>(
        head_bf, wo_bf, 4096, 1024, 1024, bo, x, nullptr, x2, nullptr);

    rmsnorm_kernel<<<4096, 256, 0, stream>>>(x2, ffw, xn_bf);

    gemm_bf16<2><<<dim3(2816 / 128, 4096 / 128), 256, 0, stream>>>(
        xn_bf, v_bf, 4096, 2816, 1024, nullptr, nullptr, nullptr, nullptr, tv_bf);

    gemm_bf16<3><<<dim3(2816 / 128, 4096 / 128), 256, 0, stream>>>(
        xn_bf, u_bf, 4096, 2816, 1024, nullptr, nullptr, tv_bf, nullptr, g_bf);

    gemm_bf16<4><<<dim3(1024 / 128, 4096 / 128), 256, 0, stream>>>(
        g_bf, w_bf, 4096, 1024, 2816, nullptr, x2, nullptr, out, nullptr);
}

// Round 3
// 386.292 us; speedup vs baseline: 2.3828x; 1.1556x over previous
//
#include <hip/hip_runtime.h>

#define B_  4
#define L_  1024
#define D_  1024
#define NH_ 16
#define DH_ 64
#define H_  2730
#define HP_ 2816
#define M_  4096  // B*L

typedef short bf16x8 __attribute__((ext_vector_type(8)));
typedef float f32x4  __attribute__((ext_vector_type(4)));

__device__ __forceinline__ unsigned short f2bf(float f) {
    unsigned int u = __builtin_bit_cast(unsigned int, f);
    u += 0x7fffu + ((u >> 16) & 1u);
    return (unsigned short)(u >> 16);
}
__device__ __forceinline__ float bf2f(unsigned short s) {
    unsigned int u = ((unsigned int)s) << 16;
    return __builtin_bit_cast(float, u);
}

__device__ __forceinline__ void glds16(const void* g, void* l) {
    __builtin_amdgcn_global_load_lds(
        (const __attribute__((address_space(1))) unsigned int*)g,
        (__attribute__((address_space(3))) unsigned int*)l, 16, 0, 0);
}

// ---------------- weight fp32 [K][N] -> bf16 transposed [Np][Kp] (zero pad) ----------------
__global__ __launch_bounds__(256) void cvtT_kernel(
    const float* __restrict__ in, unsigned short* __restrict__ out,
    int K, int N, int Kp, int Np)
{
    __shared__ float t[32][33];
    const int k0 = blockIdx.x * 32, n0 = blockIdx.y * 32;
    const int tx = threadIdx.x & 31, ty = threadIdx.x >> 5;
    #pragma unroll
    for (int i = 0; i < 4; ++i) {
        const int k = k0 + ty + i * 8, n = n0 + tx;
        t[ty + i * 8][tx] = (k < K && n < N) ? in[(size_t)k * N + n] : 0.0f;
    }
    __syncthreads();
    #pragma unroll
    for (int i = 0; i < 4; ++i) {
        const int n = n0 + ty + i * 8, k = k0 + tx;
        out[(size_t)n * Kp + k] = f2bf(t[tx][ty + i * 8]);
    }
}

// ---------------- RMSNorm: fp32 in -> bf16 out ----------------
__global__ __launch_bounds__(256) void rmsnorm_kernel(
    const float* __restrict__ x, const float* __restrict__ w,
    unsigned short* __restrict__ out)
{
    const int row = blockIdx.x;
    const int t = threadIdx.x;
    const float4 v = ((const float4*)(x + (size_t)row * 1024))[t];
    float ss = v.x*v.x + v.y*v.y + v.z*v.z + v.w*v.w;
    #pragma unroll
    for (int off = 32; off > 0; off >>= 1) ss += __shfl_down(ss, off);
    __shared__ float red[4];
    if ((t & 63) == 0) red[t >> 6] = ss;
    __syncthreads();
    const float tot = red[0] + red[1] + red[2] + red[3];
    const float rr = rsqrtf(tot * (1.0f / 1024.0f) + 1e-8f);
    const float4 wv = ((const float4*)w)[t];
    ushort4 o;
    o.x = f2bf(v.x * wv.x * rr); o.y = f2bf(v.y * wv.y * rr);
    o.z = f2bf(v.z * wv.z * rr); o.w = f2bf(v.w * wv.w * rr);
    ((ushort4*)(out + (size_t)row * 1024))[t] = o;
}

// ---------------- bf16 MFMA GEMM, 128xTN tile, BK=32, pipelined glds dbuf ----------------
// A [M][K] rows, Bt [N][K] rows (transposed weights).
// EPI: 0 = out_bf16(acc + bias)            (qkv)
//      1 = out_f32(acc + bias + res)       (wo: x + head@wo + bo)
//      2 = out_bf16(acc)                   (tv = xn@v)
//      3 = out_bf16(silu(acc) * mul)       (g)
//      4 = out_f32(acc + res)              (out = x2 + g@w)
template<int EPI, int TN>
__global__ __launch_bounds__(256) void gemm_bf16(
    const unsigned short* __restrict__ A, const unsigned short* __restrict__ Bt,
    int M, int N, int K,
    const float* __restrict__ bias, const float* __restrict__ res,
    const unsigned short* __restrict__ mul,
    float* __restrict__ outf, unsigned short* __restrict__ outb)
{
    constexpr int NS = TN / 32;                 // 4 (TN=128) or 2 (TN=64)
    constexpr int G  = (TN == 128) ? 4 : 3;     // glds16 per thread per k-tile
    constexpr int WAIT_G = 0xF70 | G;           // vmcnt(G), lgkm/exp free
    __shared__ __align__(16) unsigned short As[2][128 * 32];
    __shared__ __align__(16) unsigned short Bs[2][TN * 32];
    const int tid = threadIdx.x;
    const int m0 = blockIdx.y * 128, n0 = blockIdx.x * TN;
    const int lane = tid & 63, w = tid >> 6;
    const int wm = w >> 1, wn = w & 1;
    const int quad = lane >> 4, l15 = lane & 15;

    f32x4 acc[4][NS] = {};

    // staging map: p = w*64+lane in [0,256): row=p>>2, pos=p&3, src block c=pos^(row&3)
    const int p0 = w * 64 + lane;
    const int r0 = p0 >> 2, c0 = (p0 & 3) ^ (r0 & 3);
    const int offL0 = p0 * 8, offL1 = 2048 + p0 * 8;

    const unsigned short* Ag0 = A + (size_t)(m0 + r0) * K + c0 * 8;
    const unsigned short* Ag1 = A + (size_t)(m0 + 64 + r0) * K + c0 * 8;
    const unsigned short* Bg0 = Bt + (size_t)(n0 + r0) * K + c0 * 8;
    const unsigned short* Bg1 = Bt + (size_t)(n0 + 64 + r0) * K + c0 * 8;

    auto stage = [&](int kk, int buf) {
        glds16(Ag0 + kk, &As[buf][offL0]);
        glds16(Ag1 + kk, &As[buf][offL1]);
        glds16(Bg0 + kk, &Bs[buf][offL0]);
        if (TN == 128) glds16(Bg1 + kk, &Bs[buf][offL1]);
    };
    auto compute = [&](int buf) {
        bf16x8 af[4], bfr[NS];
        #pragma unroll
        for (int ms = 0; ms < 4; ++ms) {
            const int row = wm * 64 + ms * 16 + l15;
            af[ms] = *(const bf16x8*)&As[buf][row * 32 + ((quad ^ (row & 3)) * 8)];
        }
        #pragma unroll
        for (int ns = 0; ns < NS; ++ns) {
            const int row = wn * (TN / 2) + ns * 16 + l15;
            bfr[ns] = *(const bf16x8*)&Bs[buf][row * 32 + ((quad ^ (row & 3)) * 8)];
        }
        #pragma unroll
        for (int ms = 0; ms < 4; ++ms)
            #pragma unroll
            for (int ns = 0; ns < NS; ++ns)
                acc[ms][ns] = __builtin_amdgcn_mfma_f32_16x16x32_bf16(
                    af[ms], bfr[ns], acc[ms][ns], 0, 0, 0);
    };

    const int nk = K >> 5;  // always even here (K = 1024 or 2816)
    stage(0, 0);
    for (int i = 0; i < nk; i += 2) {
        if (i + 1 < nk) { stage((i + 1) << 5, 1); __builtin_amdgcn_s_waitcnt(WAIT_G); }
        else            { __builtin_amdgcn_s_waitcnt(0xF70); }
        __builtin_amdgcn_s_barrier();
        compute(0);
        __builtin_amdgcn_s_barrier();
        if (i + 2 < nk) { stage((i + 2) << 5, 0); __builtin_amdgcn_s_waitcnt(WAIT_G); }
        else            { __builtin_amdgcn_s_waitcnt(0xF70); }
        __builtin_amdgcn_s_barrier();
        compute(1);
        __builtin_amdgcn_s_barrier();
    }

    #pragma unroll
    for (int ms = 0; ms < 4; ++ms) {
        #pragma unroll
        for (int r = 0; r < 4; ++r) {
            const int row = m0 + wm * 64 + ms * 16 + quad * 4 + r;
            const size_t ro = (size_t)row * N;
            #pragma unroll
            for (int ns = 0; ns < NS; ++ns) {
                const int col = n0 + wn * (TN / 2) + ns * 16 + l15;
                float v = acc[ms][ns][r];
                if (EPI == 0) {
                    outb[ro + col] = f2bf(v + bias[col]);
                } else if (EPI == 1) {
                    outf[ro + col] = v + bias[col] + res[ro + col];
                } else if (EPI == 2) {
                    outb[ro + col] = f2bf(v);
                } else if (EPI == 3) {
                    float t = bf2f(mul[ro + col]);
                    float g = v / (1.0f + __expf(-v)) * t;
                    outb[ro + col] = f2bf(g);
                } else {
                    outf[ro + col] = v + res[ro + col];
                }
            }
        }
    }
}

// ---------------- MFMA flash attention: 128-query blocks, 64-key tiles ----------------
__global__ __launch_bounds__(256) void attn_mfma_kernel(
    const unsigned short* __restrict__ qkv, unsigned short* __restrict__ hout)
{
    __shared__ __align__(16) unsigned short Qs[128 * 72];
    __shared__ __align__(16) unsigned short Ks[64 * 72];
    __shared__ __align__(16) unsigned short Vt[64 * 72];  // [d][key]
    __shared__ __align__(16) unsigned short Ps[128 * 72];

    const int tid = threadIdx.x;
    const int qt = blockIdx.x, h = blockIdx.y, b = blockIdx.z;
    const int q0 = qt * 128;
    const int w = tid >> 6, lane = tid & 63;
    const int quad = lane >> 4, l15 = lane & 15;

    {
        const int row = tid >> 1, half = tid & 1;
        const unsigned short* gp = qkv + (size_t)(b * L_ + q0 + row) * 3072 + h * 64 + half * 32;
        uint4 a = *(const uint4*)gp;
        uint4 c = *(const uint4*)(gp + 8);
        uint4 d = *(const uint4*)(gp + 16);
        uint4 e = *(const uint4*)(gp + 24);
        unsigned short* dp = &Qs[row * 72 + half * 32];
        *(uint4*)dp = a; *(uint4*)(dp + 8) = c; *(uint4*)(dp + 16) = d; *(uint4*)(dp + 24) = e;
    }

    f32x4 O[2][4] = {};
    float m_st[2][4], l_st[2][4];
    #pragma unroll
    for (int qs = 0; qs < 2; ++qs)
        #pragma unroll
        for (int r = 0; r < 4; ++r) { m_st[qs][r] = -1e30f; l_st[qs][r] = 0.0f; }

    const int ktiles = 2 * qt + 2;
    const int wave_qmax = q0 + w * 32 + 31;
    const int krow = tid >> 2, kseg = tid & 3;
    const int vkey = (tid & 31) * 2, vdp = tid >> 5;

    for (int kt = 0; kt < ktiles; ++kt) {
        const int k0 = kt * 64;
        __syncthreads();
        {
            const unsigned short* gp = qkv + (size_t)(b * L_ + k0 + krow) * 3072 + 1024 + h * 64 + kseg * 16;
            uint4 a = *(const uint4*)gp;
            uint4 c = *(const uint4*)(gp + 8);
            unsigned short* dp = &Ks[krow * 72 + kseg * 16];
            *(uint4*)dp = a; *(uint4*)(dp + 8) = c;
        }
        {
            const unsigned short* gp = qkv + (size_t)(b * L_ + k0 + vkey) * 3072 + 2048 + h * 64 + vdp * 8;
            union { uint4 u; unsigned short s[8]; } v0, v1;
            v0.u = *(const uint4*)gp;
            v1.u = *(const uint4*)(gp + 3072);
            #pragma unroll
            for (int i = 0; i < 8; ++i) {
                unsigned int pk = (unsigned int)v0.s[i] | ((unsigned int)v1.s[i] << 16);
                *(unsigned int*)&Vt[(vdp * 8 + i) * 72 + vkey] = pk;
            }
        }
        __syncthreads();

        if (k0 <= wave_qmax) {
            bf16x8 af[2][2], bfk[4][2];
            #pragma unroll
            for (int qs = 0; qs < 2; ++qs)
                #pragma unroll
                for (int s = 0; s < 2; ++s)
                    af[qs][s] = *(const bf16x8*)&Qs[(w * 32 + qs * 16 + l15) * 72 + s * 32 + quad * 8];
            #pragma unroll
            for (int n = 0; n < 4; ++n)
                #pragma unroll
                for (int s = 0; s < 2; ++s)
                    bfk[n][s] = *(const bf16x8*)&Ks[(n * 16 + l15) * 72 + s * 32 + quad * 8];
            f32x4 sacc[2][4] = {};
            #pragma unroll
            for (int qs = 0; qs < 2; ++qs)
                #pragma unroll
                for (int n = 0; n < 4; ++n) {
                    sacc[qs][n] = __builtin_amdgcn_mfma_f32_16x16x32_bf16(af[qs][0], bfk[n][0], sacc[qs][n], 0, 0, 0);
                    sacc[qs][n] = __builtin_amdgcn_mfma_f32_16x16x32_bf16(af[qs][1], bfk[n][1], sacc[qs][n], 0, 0, 0);
                }

            #pragma unroll
            for (int qs = 0; qs < 2; ++qs) {
                const int rowg0 = q0 + w * 32 + qs * 16 + quad * 4;
                float p[4][4], mx[4];
                #pragma unroll
                for (int r = 0; r < 4; ++r) mx[r] = -1e30f;
                #pragma unroll
                for (int n = 0; n < 4; ++n) {
                    const int col = k0 + n * 16 + l15;
                    #pragma unroll
                    for (int r = 0; r < 4; ++r) {
                        float v = sacc[qs][n][r] * 0.03125f;
                        if (col > rowg0 + r) v = -1e30f;
                        p[n][r] = v;
                        mx[r] = fmaxf(mx[r], v);
                    }
                }
                #pragma unroll
                for (int r = 0; r < 4; ++r) {
                    #pragma unroll
                    for (int m = 1; m < 16; m <<= 1)
                        mx[r] = fmaxf(mx[r], __shfl_xor(mx[r], m));
                }
                float alpha[4], rs[4];
                #pragma unroll
                for (int r = 0; r < 4; ++r) {
                    const float mnew = fmaxf(m_st[qs][r], mx[r]);
                    alpha[r] = __expf(m_st[qs][r] - mnew);
                    m_st[qs][r] = mnew;
                    float s0 = 0.0f;
                    #pragma unroll
                    for (int n = 0; n < 4; ++n) {
                        const float e = __expf(p[n][r] - mnew);
                        p[n][r] = e;
                        s0 += e;
                    }
                    rs[r] = s0;
                }
                #pragma unroll
                for (int r = 0; r < 4; ++r) {
                    #pragma unroll
                    for (int m = 1; m < 16; m <<= 1)
                        rs[r] += __shfl_xor(rs[r], m);
                    l_st[qs][r] = l_st[qs][r] * alpha[r] + rs[r];
                }
                #pragma unroll
                for (int dn = 0; dn < 4; ++dn)
                    #pragma unroll
                    for (int r = 0; r < 4; ++r)
                        O[qs][dn][r] *= alpha[r];
                #pragma unroll
                for (int n = 0; n < 4; ++n)
                    #pragma unroll
                    for (int r = 0; r < 4; ++r)
                        Ps[(w * 32 + qs * 16 + quad * 4 + r) * 72 + n * 16 + l15] = f2bf(p[n][r]);
            }

            bf16x8 ap[2][2], bv[4][2];
            #pragma unroll
            for (int qs = 0; qs < 2; ++qs)
                #pragma unroll
                for (int s = 0; s < 2; ++s)
                    ap[qs][s] = *(const bf16x8*)&Ps[(w * 32 + qs * 16 + l15) * 72 + s * 32 + quad * 8];
            #pragma unroll
            for (int dn = 0; dn < 4; ++dn)
                #pragma unroll
                for (int s = 0; s < 2; ++s)
                    bv[dn][s] = *(const bf16x8*)&Vt[(dn * 16 + l15) * 72 + s * 32 + quad * 8];
            #pragma unroll
            for (int qs = 0; qs < 2; ++qs)
                #pragma unroll
                for (int dn = 0; dn < 4; ++dn) {
                    O[qs][dn] = __builtin_amdgcn_mfma_f32_16x16x32_bf16(ap[qs][0], bv[dn][0], O[qs][dn], 0, 0, 0);
                    O[qs][dn] = __builtin_amdgcn_mfma_f32_16x16x32_bf16(ap[qs][1], bv[dn][1], O[qs][dn], 0, 0, 0);
                }
        }
    }

    #pragma unroll
    for (int qs = 0; qs < 2; ++qs) {
        #pragma unroll
        for (int r = 0; r < 4; ++r) {
            const float inv = 1.0f / l_st[qs][r];
            const int rowg = q0 + w * 32 + qs * 16 + quad * 4 + r;
            unsigned short* op = hout + (size_t)(b * L_ + rowg) * 1024 + h * 64;
            #pragma unroll
            for (int dn = 0; dn < 4; ++dn)
                op[dn * 16 + l15] = f2bf(O[qs][dn][r] * inv);
        }
    }
}

extern "C" void kernel_launch(void* const* d_in, const int* in_sizes, int n_in,
                              void* d_out, int out_size, void* d_ws, size_t ws_size,
                              hipStream_t stream)
{
    const float* x   = (const float*)d_in[0];
    // d_in[1] = mask m — causal, implemented analytically
    const float* wx  = (const float*)d_in[2];
    const float* bx  = (const float*)d_in[3];
    const float* wo  = (const float*)d_in[4];
    const float* bo  = (const float*)d_in[5];
    const float* mhw = (const float*)d_in[6];
    const float* ffw = (const float*)d_in[7];
    const float* u   = (const float*)d_in[8];
    const float* v   = (const float*)d_in[9];
    const float* w   = (const float*)d_in[10];
    float* out = (float*)d_out;

    char* W = (char*)d_ws;
    unsigned short* xn_bf   = (unsigned short*)(W + 0);          //  8 MB [4096,1024]
    unsigned short* wx_bf   = (unsigned short*)(W + 8388608);    //  6 MB [3072,1024] (T)
    unsigned short* qkv_bf  = (unsigned short*)(W + 14680064);   // 24 MB [4096,3072]
    unsigned short* head_bf = (unsigned short*)(W + 39845888);   //  8 MB [4096,1024]
    unsigned short* wo_bf   = (unsigned short*)(W + 48234496);   //  2 MB [1024,1024] (T)
    float*          x2      = (float*)(W + 50331648);            // 16 MB [4096,1024]
    unsigned short* u_bf    = (unsigned short*)(W + 67108864);   // 5.5 MB [2816,1024] (T)
    unsigned short* v_bf    = (unsigned short*)(W + 72876032);   // 5.5 MB [2816,1024] (T)
    unsigned short* w_bf    = (unsigned short*)(W + 78643200);   // 5.5 MB [1024,2816] (T)
    unsigned short* g_bf    = (unsigned short*)(W + 84410368);   // 22 MB [4096,2816]
    unsigned short* tv_bf   = qkv_bf;  // alias: qkv dead after attention

    cvtT_kernel<<<dim3(32, 96), 256, 0, stream>>>(wx, wx_bf, 1024, 3072, 1024, 3072);
    cvtT_kernel<<<dim3(32, 32), 256, 0, stream>>>(wo, wo_bf, 1024, 1024, 1024, 1024);
    cvtT_kernel<<<dim3(32, 88), 256, 0, stream>>>(u,  u_bf, 1024, 2730, 1024, 2816);
    cvtT_kernel<<<dim3(32, 88), 256, 0, stream>>>(v,  v_bf, 1024, 2730, 1024, 2816);
    cvtT_kernel<<<dim3(88, 32), 256, 0, stream>>>(w,  w_bf, 2730, 1024, 2816, 1024);

    rmsnorm_kernel<<<4096, 256, 0, stream>>>(x, mhw, xn_bf);

    gemm_bf16<0, 128><<<dim3(3072 / 128, 32), 256, 0, stream>>>(
        xn_bf, wx_bf, 4096, 3072, 1024, bx, nullptr, nullptr, nullptr, qkv_bf);

    attn_mfma_kernel<<<dim3(8, 16, 4), 256, 0, stream>>>(qkv_bf, head_bf);

    gemm_bf16<1, 64><<<dim3(1024 / 64, 32), 256, 0, stream>>>(
        head_bf, wo_bf, 4096, 1024, 1024, bo, x, nullptr, x2, nullptr);

    rmsnorm_kernel<<<4096, 256, 0, stream>>>(x2, ffw, xn_bf);

    gemm_bf16<2, 128><<<dim3(2816 / 128, 32), 256, 0, stream>>>(
        xn_bf, v_bf, 4096, 2816, 1024, nullptr, nullptr, nullptr, nullptr, tv_bf);

    gemm_bf16<3, 128><<<dim3(2816 / 128, 32), 256, 0, stream>>>(
        xn_bf, u_bf, 4096, 2816, 1024, nullptr, nullptr, tv_bf, nullptr, g_bf);

    gemm_bf16<4, 64><<<dim3(1024 / 64, 32), 256, 0, stream>>>(
        g_bf, w_bf, 4096, 1024, 2816, nullptr, x2, nullptr, out, nullptr);
}

// Round 4
// 364.117 us; speedup vs baseline: 2.5279x; 1.0609x over previous
//
#include <hip/hip_runtime.h>

#define B_  4
#define L_  1024
#define D_  1024
#define NH_ 16
#define DH_ 64
#define H_  2730
#define HP_ 2816
#define M_  4096  // B*L

typedef short bf16x8 __attribute__((ext_vector_type(8)));
typedef float f32x4  __attribute__((ext_vector_type(4)));

__device__ __forceinline__ unsigned short f2bf(float f) {
    unsigned int u = __builtin_bit_cast(unsigned int, f);
    u += 0x7fffu + ((u >> 16) & 1u);
    return (unsigned short)(u >> 16);
}
__device__ __forceinline__ float bf2f(unsigned short s) {
    unsigned int u = ((unsigned int)s) << 16;
    return __builtin_bit_cast(float, u);
}

__device__ __forceinline__ void glds16(const void* g, void* l) {
    __builtin_amdgcn_global_load_lds(
        (const __attribute__((address_space(1))) unsigned int*)g,
        (__attribute__((address_space(3))) unsigned int*)l, 16, 0, 0);
}

// ---------------- weight fp32 [K][N] -> bf16 transposed [Np][Kp] (zero pad) ----------------
__global__ __launch_bounds__(256) void cvtT_kernel(
    const float* __restrict__ in, unsigned short* __restrict__ out,
    int K, int N, int Kp, int Np)
{
    __shared__ float t[32][33];
    const int k0 = blockIdx.x * 32, n0 = blockIdx.y * 32;
    const int tx = threadIdx.x & 31, ty = threadIdx.x >> 5;
    #pragma unroll
    for (int i = 0; i < 4; ++i) {
        const int k = k0 + ty + i * 8, n = n0 + tx;
        t[ty + i * 8][tx] = (k < K && n < N) ? in[(size_t)k * N + n] : 0.0f;
    }
    __syncthreads();
    #pragma unroll
    for (int i = 0; i < 4; ++i) {
        const int n = n0 + ty + i * 8, k = k0 + tx;
        out[(size_t)n * Kp + k] = f2bf(t[tx][ty + i * 8]);
    }
}

// ---------------- RMSNorm: fp32 in -> bf16 out ----------------
__global__ __launch_bounds__(256) void rmsnorm_kernel(
    const float* __restrict__ x, const float* __restrict__ w,
    unsigned short* __restrict__ out)
{
    const int row = blockIdx.x;
    const int t = threadIdx.x;
    const float4 v = ((const float4*)(x + (size_t)row * 1024))[t];
    float ss = v.x*v.x + v.y*v.y + v.z*v.z + v.w*v.w;
    #pragma unroll
    for (int off = 32; off > 0; off >>= 1) ss += __shfl_down(ss, off);
    __shared__ float red[4];
    if ((t & 63) == 0) red[t >> 6] = ss;
    __syncthreads();
    const float tot = red[0] + red[1] + red[2] + red[3];
    const float rr = rsqrtf(tot * (1.0f / 1024.0f) + 1e-8f);
    const float4 wv = ((const float4*)w)[t];
    ushort4 o;
    o.x = f2bf(v.x * wv.x * rr); o.y = f2bf(v.y * wv.y * rr);
    o.z = f2bf(v.z * wv.z * rr); o.w = f2bf(v.w * wv.w * rr);
    ((ushort4*)(out + (size_t)row * 1024))[t] = o;
}

// ---------------- bf16 MFMA GEMM, 128xTN tile, BK=32, pipelined glds dbuf ----------------
template<int EPI, int TN>
__global__ __launch_bounds__(256) void gemm_bf16(
    const unsigned short* __restrict__ A, const unsigned short* __restrict__ Bt,
    int M, int N, int K,
    const float* __restrict__ bias, const float* __restrict__ res,
    const unsigned short* __restrict__ mul,
    float* __restrict__ outf, unsigned short* __restrict__ outb)
{
    constexpr int NS = TN / 32;
    constexpr int G  = (TN == 128) ? 4 : 3;
    constexpr int WAIT_G = 0xF70 | G;
    __shared__ __align__(16) unsigned short As[2][128 * 32];
    __shared__ __align__(16) unsigned short Bs[2][TN * 32];
    const int tid = threadIdx.x;
    const int m0 = blockIdx.y * 128, n0 = blockIdx.x * TN;
    const int lane = tid & 63, w = tid >> 6;
    const int wm = w >> 1, wn = w & 1;
    const int quad = lane >> 4, l15 = lane & 15;

    f32x4 acc[4][NS] = {};

    const int p0 = w * 64 + lane;
    const int r0 = p0 >> 2, c0 = (p0 & 3) ^ (r0 & 3);
    const int offL0 = p0 * 8, offL1 = 2048 + p0 * 8;

    const unsigned short* Ag0 = A + (size_t)(m0 + r0) * K + c0 * 8;
    const unsigned short* Ag1 = A + (size_t)(m0 + 64 + r0) * K + c0 * 8;
    const unsigned short* Bg0 = Bt + (size_t)(n0 + r0) * K + c0 * 8;
    const unsigned short* Bg1 = Bt + (size_t)(n0 + 64 + r0) * K + c0 * 8;

    auto stage = [&](int kk, int buf) {
        glds16(Ag0 + kk, &As[buf][offL0]);
        glds16(Ag1 + kk, &As[buf][offL1]);
        glds16(Bg0 + kk, &Bs[buf][offL0]);
        if (TN == 128) glds16(Bg1 + kk, &Bs[buf][offL1]);
    };
    auto compute = [&](int buf) {
        bf16x8 af[4], bfr[NS];
        #pragma unroll
        for (int ms = 0; ms < 4; ++ms) {
            const int row = wm * 64 + ms * 16 + l15;
            af[ms] = *(const bf16x8*)&As[buf][row * 32 + ((quad ^ (row & 3)) * 8)];
        }
        #pragma unroll
        for (int ns = 0; ns < NS; ++ns) {
            const int row = wn * (TN / 2) + ns * 16 + l15;
            bfr[ns] = *(const bf16x8*)&Bs[buf][row * 32 + ((quad ^ (row & 3)) * 8)];
        }
        #pragma unroll
        for (int ms = 0; ms < 4; ++ms)
            #pragma unroll
            for (int ns = 0; ns < NS; ++ns)
                acc[ms][ns] = __builtin_amdgcn_mfma_f32_16x16x32_bf16(
                    af[ms], bfr[ns], acc[ms][ns], 0, 0, 0);
    };

    const int nk = K >> 5;
    stage(0, 0);
    for (int i = 0; i < nk; i += 2) {
        if (i + 1 < nk) { stage((i + 1) << 5, 1); __builtin_amdgcn_s_waitcnt(WAIT_G); }
        else            { __builtin_amdgcn_s_waitcnt(0xF70); }
        __builtin_amdgcn_s_barrier();
        compute(0);
        __builtin_amdgcn_s_barrier();
        if (i + 2 < nk) { stage((i + 2) << 5, 0); __builtin_amdgcn_s_waitcnt(WAIT_G); }
        else            { __builtin_amdgcn_s_waitcnt(0xF70); }
        __builtin_amdgcn_s_barrier();
        compute(1);
        __builtin_amdgcn_s_barrier();
    }

    #pragma unroll
    for (int ms = 0; ms < 4; ++ms) {
        #pragma unroll
        for (int r = 0; r < 4; ++r) {
            const int row = m0 + wm * 64 + ms * 16 + quad * 4 + r;
            const size_t ro = (size_t)row * N;
            #pragma unroll
            for (int ns = 0; ns < NS; ++ns) {
                const int col = n0 + wn * (TN / 2) + ns * 16 + l15;
                float v = acc[ms][ns][r];
                if (EPI == 0) {
                    outb[ro + col] = f2bf(v + bias[col]);
                } else if (EPI == 1) {
                    outf[ro + col] = v + bias[col] + res[ro + col];
                } else if (EPI == 2) {
                    outb[ro + col] = f2bf(v);
                } else if (EPI == 3) {
                    float t = bf2f(mul[ro + col]);
                    float g = v / (1.0f + __expf(-v)) * t;
                    outb[ro + col] = f2bf(g);
                } else {
                    outf[ro + col] = v + res[ro + col];
                }
            }
        }
    }
}

// ---------------- MFMA flash attention v2: pair-balanced, pipelined ----------------
// Block handles q-tiles qa=bx (64 rows) and qb=15-bx: exactly 17 64x64 units.
// K dbuf via global_load_lds (XOR-swizzled), V dbuf via reg roundtrip, 1 barrier/unit.
__global__ __launch_bounds__(256) void attn_mfma2_kernel(
    const unsigned short* __restrict__ qkv, unsigned short* __restrict__ hout)
{
    __shared__ __align__(16) unsigned short Qs[2][64 * 72];  // [tile][row][d] +8 pad
    __shared__ __align__(16) unsigned short Ks[2][64 * 64];  // swizzled, unpadded
    __shared__ __align__(16) unsigned short Vt[2][64 * 72];  // [d][key] +8 pad
    __shared__ __align__(16) unsigned short Ps[64 * 68];     // +4 pad (write-conflict-free)

    const int tid = threadIdx.x;
    const int qa = blockIdx.x, h = blockIdx.y, b = blockIdx.z;
    const int qb = 15 - qa;
    const int w = tid >> 6, lane = tid & 63;
    const int quad = lane >> 4, l15 = lane & 15;

    const size_t basek = (size_t)(b * L_) * 3072 + 1024 + h * 64;
    const size_t basev = basek + 1024;

    // --- stage both Q tiles (128 rows x 64 d) ---
    {
        const int row = tid >> 1, half = tid & 1;
        const int tile = row >> 6, r6 = row & 63;
        const int grow = (tile ? qb : qa) * 64 + r6;
        const unsigned short* gp = qkv + (size_t)(b * L_ + grow) * 3072 + h * 64 + half * 32;
        uint4 a = *(const uint4*)gp;
        uint4 c = *(const uint4*)(gp + 8);
        uint4 d = *(const uint4*)(gp + 16);
        uint4 e = *(const uint4*)(gp + 24);
        unsigned short* dp = &Qs[tile][r6 * 72 + half * 32];
        *(uint4*)dp = a; *(uint4*)(dp + 8) = c; *(uint4*)(dp + 16) = d; *(uint4*)(dp + 24) = e;
    }

    auto stageK = [&](int kt, int buf) {
        #pragma unroll
        for (int i = 0; i < 2; ++i) {
            const int p = i * 256 + tid;
            const int row = p >> 3;
            const int cc = (p & 7) ^ (row & 7);
            glds16(qkv + basek + (size_t)(kt * 64 + row) * 3072 + cc * 8, &Ks[buf][p * 8]);
        }
    };
    const int vkey = (tid & 31) * 2, vdp = tid >> 5;
    auto loadV = [&](int kt, uint4& v0, uint4& v1) {
        const unsigned short* gp = qkv + basev + (size_t)(kt * 64 + vkey) * 3072 + vdp * 8;
        v0 = *(const uint4*)gp;
        v1 = *(const uint4*)(gp + 3072);
    };
    auto writeV = [&](int buf, const uint4& v0, const uint4& v1) {
        union { uint4 u; unsigned short s[8]; } a, c;
        a.u = v0; c.u = v1;
        #pragma unroll
        for (int i = 0; i < 8; ++i) {
            unsigned int pk = (unsigned int)a.s[i] | ((unsigned int)c.s[i] << 16);
            *(unsigned int*)&Vt[buf][(vdp * 8 + i) * 72 + vkey] = pk;
        }
    };

    f32x4 O[4] = {};
    float m4[4], l4[4];
    #pragma unroll
    for (int r = 0; r < 4; ++r) { m4[r] = -1e30f; l4[r] = 0.0f; }

    // prologue: stage unit 0
    stageK(0, 0);
    {
        uint4 v0, v1;
        loadV(0, v0, v1);
        writeV(0, v0, v1);
    }
    __syncthreads();

    bf16x8 af[2];
    #pragma unroll
    for (int s = 0; s < 2; ++s)
        af[s] = *(const bf16x8*)&Qs[0][(w * 16 + l15) * 72 + s * 32 + quad * 8];

    int qsel = 0, kt = 0;
    for (int t = 0; t < 17; ++t) {
        const int cb = t & 1, nb = cb ^ 1;
        const bool havenext = (t < 16);
        uint4 nv0, nv1;
        if (havenext) {
            const int ktn = (t + 1 <= qa) ? (t + 1) : (t - qa);
            stageK(ktn, nb);
            loadV(ktn, nv0, nv1);
        }

        // ---- QK^T (8 MFMA) ----
        bf16x8 bfk[4][2];
        #pragma unroll
        for (int n = 0; n < 4; ++n) {
            const int row = n * 16 + l15;
            #pragma unroll
            for (int s = 0; s < 2; ++s)
                bfk[n][s] = *(const bf16x8*)&Ks[cb][row * 64 + (((s * 4 + quad) ^ (row & 7)) * 8)];
        }
        f32x4 sacc[4] = {};
        #pragma unroll
        for (int n = 0; n < 4; ++n) {
            sacc[n] = __builtin_amdgcn_mfma_f32_16x16x32_bf16(af[0], bfk[n][0], sacc[n], 0, 0, 0);
            sacc[n] = __builtin_amdgcn_mfma_f32_16x16x32_bf16(af[1], bfk[n][1], sacc[n], 0, 0, 0);
        }

        // ---- scale + mask + online softmax ----
        const bool diag = (kt == (qsel ? qb : qa));
        float p[4][4], mx[4];
        #pragma unroll
        for (int r = 0; r < 4; ++r) mx[r] = -1e30f;
        #pragma unroll
        for (int n = 0; n < 4; ++n) {
            const int col = n * 16 + l15;
            #pragma unroll
            for (int r = 0; r < 4; ++r) {
                float v = sacc[n][r] * 0.03125f;
                if (diag && col > (w * 16 + quad * 4 + r)) v = -1e30f;
                p[n][r] = v;
                mx[r] = fmaxf(mx[r], v);
            }
        }
        #pragma unroll
        for (int r = 0; r < 4; ++r) {
            #pragma unroll
            for (int m = 1; m < 16; m <<= 1)
                mx[r] = fmaxf(mx[r], __shfl_xor(mx[r], m));
        }
        float alpha[4], rs[4];
        #pragma unroll
        for (int r = 0; r < 4; ++r) {
            const float mnew = fmaxf(m4[r], mx[r]);
            alpha[r] = __expf(m4[r] - mnew);
            m4[r] = mnew;
            float s0 = 0.0f;
            #pragma unroll
            for (int n = 0; n < 4; ++n) {
                const float e = __expf(p[n][r] - mnew);
                p[n][r] = e;
                s0 += e;
            }
            rs[r] = s0;
        }
        #pragma unroll
        for (int r = 0; r < 4; ++r) {
            #pragma unroll
            for (int m = 1; m < 16; m <<= 1)
                rs[r] += __shfl_xor(rs[r], m);
            l4[r] = l4[r] * alpha[r] + rs[r];
        }
        #pragma unroll
        for (int dn = 0; dn < 4; ++dn)
            #pragma unroll
            for (int r = 0; r < 4; ++r)
                O[dn][r] *= alpha[r];
        #pragma unroll
        for (int n = 0; n < 4; ++n)
            #pragma unroll
            for (int r = 0; r < 4; ++r)
                Ps[(w * 16 + quad * 4 + r) * 68 + n * 16 + l15] = f2bf(p[n][r]);

        // stage V for next unit into other buffer (safe: prev reads of nb done pre-barrier)
        if (havenext) writeV(nb, nv0, nv1);

        // ---- O += P V (8 MFMA) ----
        bf16x8 ap[2], bv[4][2];
        #pragma unroll
        for (int s = 0; s < 2; ++s)
            ap[s] = *(const bf16x8*)&Ps[(w * 16 + l15) * 68 + s * 32 + quad * 8];
        #pragma unroll
        for (int dn = 0; dn < 4; ++dn)
            #pragma unroll
            for (int s = 0; s < 2; ++s)
                bv[dn][s] = *(const bf16x8*)&Vt[cb][(dn * 16 + l15) * 72 + s * 32 + quad * 8];
        #pragma unroll
        for (int dn = 0; dn < 4; ++dn) {
            O[dn] = __builtin_amdgcn_mfma_f32_16x16x32_bf16(ap[0], bv[dn][0], O[dn], 0, 0, 0);
            O[dn] = __builtin_amdgcn_mfma_f32_16x16x32_bf16(ap[1], bv[dn][1], O[dn], 0, 0, 0);
        }

        // phase transition: finalize A, reset state, switch to B
        if (t == qa) {
            #pragma unroll
            for (int r = 0; r < 4; ++r) {
                const float inv = 1.0f / l4[r];
                const int grow = qa * 64 + w * 16 + quad * 4 + r;
                unsigned short* op = hout + (size_t)(b * L_ + grow) * 1024 + h * 64;
                #pragma unroll
                for (int dn = 0; dn < 4; ++dn)
                    op[dn * 16 + l15] = f2bf(O[dn][r] * inv);
            }
            #pragma unroll
            for (int dn = 0; dn < 4; ++dn)
                #pragma unroll
                for (int r = 0; r < 4; ++r) O[dn][r] = 0.0f;
            #pragma unroll
            for (int r = 0; r < 4; ++r) { m4[r] = -1e30f; l4[r] = 0.0f; }
            qsel = 1;
            kt = 0;
            #pragma unroll
            for (int s = 0; s < 2; ++s)
                af[s] = *(const bf16x8*)&Qs[1][(w * 16 + l15) * 72 + s * 32 + quad * 8];
        } else {
            ++kt;
        }
        __syncthreads();
    }

    // finalize B
    #pragma unroll
    for (int r = 0; r < 4; ++r) {
        const float inv = 1.0f / l4[r];
        const int grow = qb * 64 + w * 16 + quad * 4 + r;
        unsigned short* op = hout + (size_t)(b * L_ + grow) * 1024 + h * 64;
        #pragma unroll
        for (int dn = 0; dn < 4; ++dn)
            op[dn * 16 + l15] = f2bf(O[dn][r] * inv);
    }
}

extern "C" void kernel_launch(void* const* d_in, const int* in_sizes, int n_in,
                              void* d_out, int out_size, void* d_ws, size_t ws_size,
                              hipStream_t stream)
{
    const float* x   = (const float*)d_in[0];
    const float* wx  = (const float*)d_in[2];
    const float* bx  = (const float*)d_in[3];
    const float* wo  = (const float*)d_in[4];
    const float* bo  = (const float*)d_in[5];
    const float* mhw = (const float*)d_in[6];
    const float* ffw = (const float*)d_in[7];
    const float* u   = (const float*)d_in[8];
    const float* v   = (const float*)d_in[9];
    const float* w   = (const float*)d_in[10];
    float* out = (float*)d_out;

    char* W = (char*)d_ws;
    unsigned short* xn_bf   = (unsigned short*)(W + 0);
    unsigned short* wx_bf   = (unsigned short*)(W + 8388608);
    unsigned short* qkv_bf  = (unsigned short*)(W + 14680064);
    unsigned short* head_bf = (unsigned short*)(W + 39845888);
    unsigned short* wo_bf   = (unsigned short*)(W + 48234496);
    float*          x2      = (float*)(W + 50331648);
    unsigned short* u_bf    = (unsigned short*)(W + 67108864);
    unsigned short* v_bf    = (unsigned short*)(W + 72876032);
    unsigned short* w_bf    = (unsigned short*)(W + 78643200);
    unsigned short* g_bf    = (unsigned short*)(W + 84410368);
    unsigned short* tv_bf   = qkv_bf;

    cvtT_kernel<<<dim3(32, 96), 256, 0, stream>>>(wx, wx_bf, 1024, 3072, 1024, 3072);
    cvtT_kernel<<<dim3(32, 32), 256, 0, stream>>>(wo, wo_bf, 1024, 1024, 1024, 1024);
    cvtT_kernel<<<dim3(32, 88), 256, 0, stream>>>(u,  u_bf, 1024, 2730, 1024, 2816);
    cvtT_kernel<<<dim3(32, 88), 256, 0, stream>>>(v,  v_bf, 1024, 2730, 1024, 2816);
    cvtT_kernel<<<dim3(88, 32), 256, 0, stream>>>(w,  w_bf, 2730, 1024, 2816, 1024);

    rmsnorm_kernel<<<4096, 256, 0, stream>>>(x, mhw, xn_bf);

    gemm_bf16<0, 128><<<dim3(3072 / 128, 32), 256, 0, stream>>>(
        xn_bf, wx_bf, 4096, 3072, 1024, bx, nullptr, nullptr, nullptr, qkv_bf);

    attn_mfma2_kernel<<<dim3(8, 16, 4), 256, 0, stream>>>(qkv_bf, head_bf);

    gemm_bf16<1, 64><<<dim3(1024 / 64, 32), 256, 0, stream>>>(
        head_bf, wo_bf, 4096, 1024, 1024, bo, x, nullptr, x2, nullptr);

    rmsnorm_kernel<<<4096, 256, 0, stream>>>(x2, ffw, xn_bf);

    gemm_bf16<2, 128><<<dim3(2816 / 128, 32), 256, 0, stream>>>(
        xn_bf, v_bf, 4096, 2816, 1024, nullptr, nullptr, nullptr, nullptr, tv_bf);

    gemm_bf16<3, 128><<<dim3(2816 / 128, 32), 256, 0, stream>>>(
        xn_bf, u_bf, 4096, 2816, 1024, nullptr, nullptr, tv_bf, nullptr, g_bf);

    gemm_bf16<4, 64><<<dim3(1024 / 64, 32), 256, 0, stream>>>(
        g_bf, w_bf, 4096, 1024, 2816, nullptr, x2, nullptr, out, nullptr);
}

// Round 5
// 360.067 us; speedup vs baseline: 2.5564x; 1.0112x over previous
//
#include <hip/hip_runtime.h>

#define B_  4
#define L_  1024
#define D_  1024
#define NH_ 16
#define DH_ 64
#define H_  2730
#define HP_ 2816
#define M_  4096  // B*L

typedef short bf16x8 __attribute__((ext_vector_type(8)));
typedef float f32x4  __attribute__((ext_vector_type(4)));

__device__ __forceinline__ unsigned short f2bf(float f) {
    unsigned int u = __builtin_bit_cast(unsigned int, f);
    u += 0x7fffu + ((u >> 16) & 1u);
    return (unsigned short)(u >> 16);
}
__device__ __forceinline__ float bf2f(unsigned short s) {
    unsigned int u = ((unsigned int)s) << 16;
    return __builtin_bit_cast(float, u);
}

__device__ __forceinline__ void glds16(const void* g, void* l) {
    __builtin_amdgcn_global_load_lds(
        (const __attribute__((address_space(1))) unsigned int*)g,
        (__attribute__((address_space(3))) unsigned int*)l, 16, 0, 0);
}

// XCD swizzle: same row-stripe (ly) -> same flat%8 -> same XCD L2.
// Requires gridDim.y % 8 == 0 (all GEMMs here have gridY = 32).
__device__ __forceinline__ void xcd_swz(int& lx, int& ly) {
    const int gx = gridDim.x;
    const int flat = blockIdx.x + gx * blockIdx.y;
    const int r = flat & 7, q = flat >> 3;
    lx = q % gx;
    ly = r + 8 * (q / gx);
}

// ---------------- weight fp32 [K][N] -> bf16 transposed [Np][Kp] (zero pad) ----------------
__global__ __launch_bounds__(256) void cvtT_kernel(
    const float* __restrict__ in, unsigned short* __restrict__ out,
    int K, int N, int Kp, int Np)
{
    __shared__ float t[32][33];
    const int k0 = blockIdx.x * 32, n0 = blockIdx.y * 32;
    const int tx = threadIdx.x & 31, ty = threadIdx.x >> 5;
    #pragma unroll
    for (int i = 0; i < 4; ++i) {
        const int k = k0 + ty + i * 8, n = n0 + tx;
        t[ty + i * 8][tx] = (k < K && n < N) ? in[(size_t)k * N + n] : 0.0f;
    }
    __syncthreads();
    #pragma unroll
    for (int i = 0; i < 4; ++i) {
        const int n = n0 + ty + i * 8, k = k0 + tx;
        out[(size_t)n * Kp + k] = f2bf(t[tx][ty + i * 8]);
    }
}

// ---------------- RMSNorm: fp32 in -> bf16 out ----------------
__global__ __launch_bounds__(256) void rmsnorm_kernel(
    const float* __restrict__ x, const float* __restrict__ w,
    unsigned short* __restrict__ out)
{
    const int row = blockIdx.x;
    const int t = threadIdx.x;
    const float4 v = ((const float4*)(x + (size_t)row * 1024))[t];
    float ss = v.x*v.x + v.y*v.y + v.z*v.z + v.w*v.w;
    #pragma unroll
    for (int off = 32; off > 0; off >>= 1) ss += __shfl_down(ss, off);
    __shared__ float red[4];
    if ((t & 63) == 0) red[t >> 6] = ss;
    __syncthreads();
    const float tot = red[0] + red[1] + red[2] + red[3];
    const float rr = rsqrtf(tot * (1.0f / 1024.0f) + 1e-8f);
    const float4 wv = ((const float4*)w)[t];
    ushort4 o;
    o.x = f2bf(v.x * wv.x * rr); o.y = f2bf(v.y * wv.y * rr);
    o.z = f2bf(v.z * wv.z * rr); o.w = f2bf(v.w * wv.w * rr);
    ((ushort4*)(out + (size_t)row * 1024))[t] = o;
}

// ---------------- bf16 MFMA GEMM, 128xTN tile, BK=32, pipelined glds dbuf ----------------
// EPI: 0 = out_bf16(acc + bias); 1 = out_f32(acc + bias + res); 4 = out_f32(acc + res)
template<int EPI, int TN>
__global__ __launch_bounds__(256) void gemm_bf16(
    const unsigned short* __restrict__ A, const unsigned short* __restrict__ Bt,
    int M, int N, int K,
    const float* __restrict__ bias, const float* __restrict__ res,
    float* __restrict__ outf, unsigned short* __restrict__ outb)
{
    constexpr int NS = TN / 32;
    constexpr int G  = (TN == 128) ? 4 : 3;
    constexpr int WAIT_G = 0xF70 | G;
    __shared__ __align__(16) unsigned short As[2][128 * 32];
    __shared__ __align__(16) unsigned short Bs[2][TN * 32];
    const int tid = threadIdx.x;
    int lx, ly;
    xcd_swz(lx, ly);
    const int m0 = ly * 128, n0 = lx * TN;
    const int lane = tid & 63, w = tid >> 6;
    const int wm = w >> 1, wn = w & 1;
    const int quad = lane >> 4, l15 = lane & 15;

    f32x4 acc[4][NS] = {};

    const int p0 = w * 64 + lane;
    const int r0 = p0 >> 2, c0 = (p0 & 3) ^ (r0 & 3);
    const int offL0 = p0 * 8, offL1 = 2048 + p0 * 8;

    const unsigned short* Ag0 = A + (size_t)(m0 + r0) * K + c0 * 8;
    const unsigned short* Ag1 = A + (size_t)(m0 + 64 + r0) * K + c0 * 8;
    const unsigned short* Bg0 = Bt + (size_t)(n0 + r0) * K + c0 * 8;
    const unsigned short* Bg1 = Bt + (size_t)(n0 + 64 + r0) * K + c0 * 8;

    auto stage = [&](int kk, int buf) {
        glds16(Ag0 + kk, &As[buf][offL0]);
        glds16(Ag1 + kk, &As[buf][offL1]);
        glds16(Bg0 + kk, &Bs[buf][offL0]);
        if (TN == 128) glds16(Bg1 + kk, &Bs[buf][offL1]);
    };
    auto compute = [&](int buf) {
        bf16x8 af[4], bfr[NS];
        #pragma unroll
        for (int ms = 0; ms < 4; ++ms) {
            const int row = wm * 64 + ms * 16 + l15;
            af[ms] = *(const bf16x8*)&As[buf][row * 32 + ((quad ^ (row & 3)) * 8)];
        }
        #pragma unroll
        for (int ns = 0; ns < NS; ++ns) {
            const int row = wn * (TN / 2) + ns * 16 + l15;
            bfr[ns] = *(const bf16x8*)&Bs[buf][row * 32 + ((quad ^ (row & 3)) * 8)];
        }
        #pragma unroll
        for (int ms = 0; ms < 4; ++ms)
            #pragma unroll
            for (int ns = 0; ns < NS; ++ns)
                acc[ms][ns] = __builtin_amdgcn_mfma_f32_16x16x32_bf16(
                    af[ms], bfr[ns], acc[ms][ns], 0, 0, 0);
    };

    const int nk = K >> 5;
    stage(0, 0);
    for (int i = 0; i < nk; i += 2) {
        if (i + 1 < nk) { stage((i + 1) << 5, 1); __builtin_amdgcn_s_waitcnt(WAIT_G); }
        else            { __builtin_amdgcn_s_waitcnt(0xF70); }
        __builtin_amdgcn_s_barrier();
        compute(0);
        __builtin_amdgcn_s_barrier();
        if (i + 2 < nk) { stage((i + 2) << 5, 0); __builtin_amdgcn_s_waitcnt(WAIT_G); }
        else            { __builtin_amdgcn_s_waitcnt(0xF70); }
        __builtin_amdgcn_s_barrier();
        compute(1);
        __builtin_amdgcn_s_barrier();
    }

    #pragma unroll
    for (int ms = 0; ms < 4; ++ms) {
        #pragma unroll
        for (int r = 0; r < 4; ++r) {
            const int row = m0 + wm * 64 + ms * 16 + quad * 4 + r;
            const size_t ro = (size_t)row * N;
            #pragma unroll
            for (int ns = 0; ns < NS; ++ns) {
                const int col = n0 + wn * (TN / 2) + ns * 16 + l15;
                float v = acc[ms][ns][r];
                if (EPI == 0) {
                    outb[ro + col] = f2bf(v + bias[col]);
                } else if (EPI == 1) {
                    outf[ro + col] = v + bias[col] + res[ro + col];
                } else {
                    outf[ro + col] = v + res[ro + col];
                }
            }
        }
    }
}

// ---------------- fused SwiGLU GEMM: g = silu(A@U^T) * (A@V^T), 128x128 tile ----------------
__global__ __launch_bounds__(256, 2) void gemm_swiglu(
    const unsigned short* __restrict__ A, const unsigned short* __restrict__ Bu,
    const unsigned short* __restrict__ Bv, unsigned short* __restrict__ g)
{
    constexpr int K = 1024, N = HP_;
    constexpr int WAIT_G = 0xF76;  // vmcnt(6)
    __shared__ __align__(16) unsigned short As[2][128 * 32];
    __shared__ __align__(16) unsigned short Us[2][128 * 32];
    __shared__ __align__(16) unsigned short Vs[2][128 * 32];
    const int tid = threadIdx.x;
    int lx, ly;
    xcd_swz(lx, ly);
    const int m0 = ly * 128, n0 = lx * 128;
    const int lane = tid & 63, w = tid >> 6;
    const int wm = w >> 1, wn = w & 1;
    const int quad = lane >> 4, l15 = lane & 15;

    f32x4 au[4][4] = {}, av[4][4] = {};

    const int p0 = w * 64 + lane;
    const int r0 = p0 >> 2, c0 = (p0 & 3) ^ (r0 & 3);
    const int offL0 = p0 * 8, offL1 = 2048 + p0 * 8;

    const unsigned short* Ag0 = A  + (size_t)(m0 + r0) * K + c0 * 8;
    const unsigned short* Ag1 = A  + (size_t)(m0 + 64 + r0) * K + c0 * 8;
    const unsigned short* Ug0 = Bu + (size_t)(n0 + r0) * K + c0 * 8;
    const unsigned short* Ug1 = Bu + (size_t)(n0 + 64 + r0) * K + c0 * 8;
    const unsigned short* Vg0 = Bv + (size_t)(n0 + r0) * K + c0 * 8;
    const unsigned short* Vg1 = Bv + (size_t)(n0 + 64 + r0) * K + c0 * 8;

    auto stage = [&](int kk, int buf) {
        glds16(Ag0 + kk, &As[buf][offL0]);
        glds16(Ag1 + kk, &As[buf][offL1]);
        glds16(Ug0 + kk, &Us[buf][offL0]);
        glds16(Ug1 + kk, &Us[buf][offL1]);
        glds16(Vg0 + kk, &Vs[buf][offL0]);
        glds16(Vg1 + kk, &Vs[buf][offL1]);
    };
    auto compute = [&](int buf) {
        bf16x8 af[4], uf[4], vf[4];
        #pragma unroll
        for (int ms = 0; ms < 4; ++ms) {
            const int row = wm * 64 + ms * 16 + l15;
            af[ms] = *(const bf16x8*)&As[buf][row * 32 + ((quad ^ (row & 3)) * 8)];
        }
        #pragma unroll
        for (int ns = 0; ns < 4; ++ns) {
            const int row = wn * 64 + ns * 16 + l15;
            uf[ns] = *(const bf16x8*)&Us[buf][row * 32 + ((quad ^ (row & 3)) * 8)];
            vf[ns] = *(const bf16x8*)&Vs[buf][row * 32 + ((quad ^ (row & 3)) * 8)];
        }
        #pragma unroll
        for (int ms = 0; ms < 4; ++ms)
            #pragma unroll
            for (int ns = 0; ns < 4; ++ns) {
                au[ms][ns] = __builtin_amdgcn_mfma_f32_16x16x32_bf16(af[ms], uf[ns], au[ms][ns], 0, 0, 0);
                av[ms][ns] = __builtin_amdgcn_mfma_f32_16x16x32_bf16(af[ms], vf[ns], av[ms][ns], 0, 0, 0);
            }
    };

    stage(0, 0);
    for (int i = 0; i < 32; i += 2) {
        if (i + 1 < 32) { stage((i + 1) << 5, 1); __builtin_amdgcn_s_waitcnt(WAIT_G); }
        else            { __builtin_amdgcn_s_waitcnt(0xF70); }
        __builtin_amdgcn_s_barrier();
        compute(0);
        __builtin_amdgcn_s_barrier();
        if (i + 2 < 32) { stage((i + 2) << 5, 0); __builtin_amdgcn_s_waitcnt(WAIT_G); }
        else            { __builtin_amdgcn_s_waitcnt(0xF70); }
        __builtin_amdgcn_s_barrier();
        compute(1);
        __builtin_amdgcn_s_barrier();
    }

    #pragma unroll
    for (int ms = 0; ms < 4; ++ms) {
        #pragma unroll
        for (int r = 0; r < 4; ++r) {
            const int row = m0 + wm * 64 + ms * 16 + quad * 4 + r;
            const size_t ro = (size_t)row * N;
            #pragma unroll
            for (int ns = 0; ns < 4; ++ns) {
                const int col = n0 + wn * 64 + ns * 16 + l15;
                const float uu = au[ms][ns][r];
                const float vv = av[ms][ns][r];
                g[ro + col] = f2bf(uu / (1.0f + __expf(-uu)) * vv);
            }
        }
    }
}

// ---------------- MFMA flash attention v2: pair-balanced, pipelined ----------------
__global__ __launch_bounds__(256) void attn_mfma2_kernel(
    const unsigned short* __restrict__ qkv, unsigned short* __restrict__ hout)
{
    __shared__ __align__(16) unsigned short Qs[2][64 * 72];
    __shared__ __align__(16) unsigned short Ks[2][64 * 64];
    __shared__ __align__(16) unsigned short Vt[2][64 * 72];
    __shared__ __align__(16) unsigned short Ps[64 * 68];

    const int tid = threadIdx.x;
    const int qa = blockIdx.x, h = blockIdx.y, b = blockIdx.z;
    const int qb = 15 - qa;
    const int w = tid >> 6, lane = tid & 63;
    const int quad = lane >> 4, l15 = lane & 15;

    const size_t basek = (size_t)(b * L_) * 3072 + 1024 + h * 64;
    const size_t basev = basek + 1024;

    {
        const int row = tid >> 1, half = tid & 1;
        const int tile = row >> 6, r6 = row & 63;
        const int grow = (tile ? qb : qa) * 64 + r6;
        const unsigned short* gp = qkv + (size_t)(b * L_ + grow) * 3072 + h * 64 + half * 32;
        uint4 a = *(const uint4*)gp;
        uint4 c = *(const uint4*)(gp + 8);
        uint4 d = *(const uint4*)(gp + 16);
        uint4 e = *(const uint4*)(gp + 24);
        unsigned short* dp = &Qs[tile][r6 * 72 + half * 32];
        *(uint4*)dp = a; *(uint4*)(dp + 8) = c; *(uint4*)(dp + 16) = d; *(uint4*)(dp + 24) = e;
    }

    auto stageK = [&](int kt, int buf) {
        #pragma unroll
        for (int i = 0; i < 2; ++i) {
            const int p = i * 256 + tid;
            const int row = p >> 3;
            const int cc = (p & 7) ^ (row & 7);
            glds16(qkv + basek + (size_t)(kt * 64 + row) * 3072 + cc * 8, &Ks[buf][p * 8]);
        }
    };
    const int vkey = (tid & 31) * 2, vdp = tid >> 5;
    auto loadV = [&](int kt, uint4& v0, uint4& v1) {
        const unsigned short* gp = qkv + basev + (size_t)(kt * 64 + vkey) * 3072 + vdp * 8;
        v0 = *(const uint4*)gp;
        v1 = *(const uint4*)(gp + 3072);
    };
    auto writeV = [&](int buf, const uint4& v0, const uint4& v1) {
        union { uint4 u; unsigned short s[8]; } a, c;
        a.u = v0; c.u = v1;
        #pragma unroll
        for (int i = 0; i < 8; ++i) {
            unsigned int pk = (unsigned int)a.s[i] | ((unsigned int)c.s[i] << 16);
            *(unsigned int*)&Vt[buf][(vdp * 8 + i) * 72 + vkey] = pk;
        }
    };

    f32x4 O[4] = {};
    float m4[4], l4[4];
    #pragma unroll
    for (int r = 0; r < 4; ++r) { m4[r] = -1e30f; l4[r] = 0.0f; }

    stageK(0, 0);
    {
        uint4 v0, v1;
        loadV(0, v0, v1);
        writeV(0, v0, v1);
    }
    __syncthreads();

    bf16x8 af[2];
    #pragma unroll
    for (int s = 0; s < 2; ++s)
        af[s] = *(const bf16x8*)&Qs[0][(w * 16 + l15) * 72 + s * 32 + quad * 8];

    int qsel = 0, kt = 0;
    for (int t = 0; t < 17; ++t) {
        const int cb = t & 1, nb = cb ^ 1;
        const bool havenext = (t < 16);
        uint4 nv0, nv1;
        if (havenext) {
            const int ktn = (t + 1 <= qa) ? (t + 1) : (t - qa);
            stageK(ktn, nb);
            loadV(ktn, nv0, nv1);
        }

        bf16x8 bfk[4][2];
        #pragma unroll
        for (int n = 0; n < 4; ++n) {
            const int row = n * 16 + l15;
            #pragma unroll
            for (int s = 0; s < 2; ++s)
                bfk[n][s] = *(const bf16x8*)&Ks[cb][row * 64 + (((s * 4 + quad) ^ (row & 7)) * 8)];
        }
        f32x4 sacc[4] = {};
        #pragma unroll
        for (int n = 0; n < 4; ++n) {
            sacc[n] = __builtin_amdgcn_mfma_f32_16x16x32_bf16(af[0], bfk[n][0], sacc[n], 0, 0, 0);
            sacc[n] = __builtin_amdgcn_mfma_f32_16x16x32_bf16(af[1], bfk[n][1], sacc[n], 0, 0, 0);
        }

        const bool diag = (kt == (qsel ? qb : qa));
        float p[4][4], mx[4];
        #pragma unroll
        for (int r = 0; r < 4; ++r) mx[r] = -1e30f;
        #pragma unroll
        for (int n = 0; n < 4; ++n) {
            const int col = n * 16 + l15;
            #pragma unroll
            for (int r = 0; r < 4; ++r) {
                float v = sacc[n][r] * 0.03125f;
                if (diag && col > (w * 16 + quad * 4 + r)) v = -1e30f;
                p[n][r] = v;
                mx[r] = fmaxf(mx[r], v);
            }
        }
        #pragma unroll
        for (int r = 0; r < 4; ++r) {
            #pragma unroll
            for (int m = 1; m < 16; m <<= 1)
                mx[r] = fmaxf(mx[r], __shfl_xor(mx[r], m));
        }
        float alpha[4], rs[4];
        #pragma unroll
        for (int r = 0; r < 4; ++r) {
            const float mnew = fmaxf(m4[r], mx[r]);
            alpha[r] = __expf(m4[r] - mnew);
            m4[r] = mnew;
            float s0 = 0.0f;
            #pragma unroll
            for (int n = 0; n < 4; ++n) {
                const float e = __expf(p[n][r] - mnew);
                p[n][r] = e;
                s0 += e;
            }
            rs[r] = s0;
        }
        #pragma unroll
        for (int r = 0; r < 4; ++r) {
            #pragma unroll
            for (int m = 1; m < 16; m <<= 1)
                rs[r] += __shfl_xor(rs[r], m);
            l4[r] = l4[r] * alpha[r] + rs[r];
        }
        #pragma unroll
        for (int dn = 0; dn < 4; ++dn)
            #pragma unroll
            for (int r = 0; r < 4; ++r)
                O[dn][r] *= alpha[r];
        #pragma unroll
        for (int n = 0; n < 4; ++n)
            #pragma unroll
            for (int r = 0; r < 4; ++r)
                Ps[(w * 16 + quad * 4 + r) * 68 + n * 16 + l15] = f2bf(p[n][r]);

        if (havenext) writeV(nb, nv0, nv1);

        bf16x8 ap[2], bv[4][2];
        #pragma unroll
        for (int s = 0; s < 2; ++s)
            ap[s] = *(const bf16x8*)&Ps[(w * 16 + l15) * 68 + s * 32 + quad * 8];
        #pragma unroll
        for (int dn = 0; dn < 4; ++dn)
            #pragma unroll
            for (int s = 0; s < 2; ++s)
                bv[dn][s] = *(const bf16x8*)&Vt[cb][(dn * 16 + l15) * 72 + s * 32 + quad * 8];
        #pragma unroll
        for (int dn = 0; dn < 4; ++dn) {
            O[dn] = __builtin_amdgcn_mfma_f32_16x16x32_bf16(ap[0], bv[dn][0], O[dn], 0, 0, 0);
            O[dn] = __builtin_amdgcn_mfma_f32_16x16x32_bf16(ap[1], bv[dn][1], O[dn], 0, 0, 0);
        }

        if (t == qa) {
            #pragma unroll
            for (int r = 0; r < 4; ++r) {
                const float inv = 1.0f / l4[r];
                const int grow = qa * 64 + w * 16 + quad * 4 + r;
                unsigned short* op = hout + (size_t)(b * L_ + grow) * 1024 + h * 64;
                #pragma unroll
                for (int dn = 0; dn < 4; ++dn)
                    op[dn * 16 + l15] = f2bf(O[dn][r] * inv);
            }
            #pragma unroll
            for (int dn = 0; dn < 4; ++dn)
                #pragma unroll
                for (int r = 0; r < 4; ++r) O[dn][r] = 0.0f;
            #pragma unroll
            for (int r = 0; r < 4; ++r) { m4[r] = -1e30f; l4[r] = 0.0f; }
            qsel = 1;
            kt = 0;
            #pragma unroll
            for (int s = 0; s < 2; ++s)
                af[s] = *(const bf16x8*)&Qs[1][(w * 16 + l15) * 72 + s * 32 + quad * 8];
        } else {
            ++kt;
        }
        __syncthreads();
    }

    #pragma unroll
    for (int r = 0; r < 4; ++r) {
        const float inv = 1.0f / l4[r];
        const int grow = qb * 64 + w * 16 + quad * 4 + r;
        unsigned short* op = hout + (size_t)(b * L_ + grow) * 1024 + h * 64;
        #pragma unroll
        for (int dn = 0; dn < 4; ++dn)
            op[dn * 16 + l15] = f2bf(O[dn][r] * inv);
    }
}

extern "C" void kernel_launch(void* const* d_in, const int* in_sizes, int n_in,
                              void* d_out, int out_size, void* d_ws, size_t ws_size,
                              hipStream_t stream)
{
    const float* x   = (const float*)d_in[0];
    const float* wx  = (const float*)d_in[2];
    const float* bx  = (const float*)d_in[3];
    const float* wo  = (const float*)d_in[4];
    const float* bo  = (const float*)d_in[5];
    const float* mhw = (const float*)d_in[6];
    const float* ffw = (const float*)d_in[7];
    const float* u   = (const float*)d_in[8];
    const float* v   = (const float*)d_in[9];
    const float* w   = (const float*)d_in[10];
    float* out = (float*)d_out;

    char* W = (char*)d_ws;
    unsigned short* xn_bf   = (unsigned short*)(W + 0);
    unsigned short* wx_bf   = (unsigned short*)(W + 8388608);
    unsigned short* qkv_bf  = (unsigned short*)(W + 14680064);
    unsigned short* head_bf = (unsigned short*)(W + 39845888);
    unsigned short* wo_bf   = (unsigned short*)(W + 48234496);
    float*          x2      = (float*)(W + 50331648);
    unsigned short* u_bf    = (unsigned short*)(W + 67108864);
    unsigned short* v_bf    = (unsigned short*)(W + 72876032);
    unsigned short* w_bf    = (unsigned short*)(W + 78643200);
    unsigned short* g_bf    = (unsigned short*)(W + 84410368);

    cvtT_kernel<<<dim3(32, 96), 256, 0, stream>>>(wx, wx_bf, 1024, 3072, 1024, 3072);
    cvtT_kernel<<<dim3(32, 32), 256, 0, stream>>>(wo, wo_bf, 1024, 1024, 1024, 1024);
    cvtT_kernel<<<dim3(32, 88), 256, 0, stream>>>(u,  u_bf, 1024, 2730, 1024, 2816);
    cvtT_kernel<<<dim3(32, 88), 256, 0, stream>>>(v,  v_bf, 1024, 2730, 1024, 2816);
    cvtT_kernel<<<dim3(88, 32), 256, 0, stream>>>(w,  w_bf, 2730, 1024, 2816, 1024);

    rmsnorm_kernel<<<4096, 256, 0, stream>>>(x, mhw, xn_bf);

    gemm_bf16<0, 128><<<dim3(3072 / 128, 32), 256, 0, stream>>>(
        xn_bf, wx_bf, 4096, 3072, 1024, bx, nullptr, nullptr, qkv_bf);

    attn_mfma2_kernel<<<dim3(8, 16, 4), 256, 0, stream>>>(qkv_bf, head_bf);

    gemm_bf16<1, 64><<<dim3(1024 / 64, 32), 256, 0, stream>>>(
        head_bf, wo_bf, 4096, 1024, 1024, bo, x, x2, nullptr);

    rmsnorm_kernel<<<4096, 256, 0, stream>>>(x2, ffw, xn_bf);

    gemm_swiglu<<<dim3(2816 / 128, 32), 256, 0, stream>>>(xn_bf, u_bf, v_bf, g_bf);

    gemm_bf16<4, 64><<<dim3(1024 / 64, 32), 256, 0, stream>>>(
        g_bf, w_bf, 4096, 1024, 2816, nullptr, x2, out, nullptr);
}